// Round 2
// baseline (745.295 us; speedup 1.0000x reference)
//
#include <hip/hip_runtime.h>
#include <hip/hip_bf16.h>

// Fused skeleton-transformer block, fp32-vector baseline (round 1: fp32 I/O).
// N=8, T=1600 (F=64 frames x V=25 joints), DIM=216, H=6, HD=36.

#define NHEAD  6
#define TLEN   1600
#define DIMC   216
#define HDIM   36
#define NBATCH 8
#define MROWS  12800          // NBATCH * TLEN
#define BUF_ELEMS 2764800     // MROWS * DIMC
#define QK_SCALE 0.16666666666666666f   // HD^-0.5 = 1/6

using bf16 = __hip_bfloat16;

// ---------------------------------------------------------------------------
// Bias tables: tbl_t (127 x 6) expanded per-head, hop table expanded to
// bias_h[h][25][25].  One block of 256 threads.
// ---------------------------------------------------------------------------
__global__ __launch_bounds__(256) void bias_tables_kernel(
    const float* __restrict__ t_w1, const float* __restrict__ t_b1,
    const float* __restrict__ t_w2, const float* __restrict__ t_b2,
    const float* __restrict__ h_w1, const float* __restrict__ h_b1,
    const float* __restrict__ h_w2, const float* __restrict__ h_b2,
    const int*  __restrict__ hop,
    float* __restrict__ bias_t,   // [6][127]
    float* __restrict__ bias_h)   // [6][625]
{
  __shared__ float tblh[16][NHEAD];
  int tid = threadIdx.x;
  if (tid < 127) {
    float xi = (float)(tid - 63);
    float acc[NHEAD] = {0.f,0.f,0.f,0.f,0.f,0.f};
    for (int d = 0; d < DIMC; ++d) {
      float r = fmaxf(fmaf(xi, t_w1[d], t_b1[d]), 0.f);
      #pragma unroll
      for (int h = 0; h < NHEAD; ++h) acc[h] = fmaf(r, t_w2[h*DIMC + d], acc[h]);
    }
    #pragma unroll
    for (int h = 0; h < NHEAD; ++h) bias_t[h*127 + tid] = acc[h] + t_b2[h];
  }
  if (tid >= 128 && tid < 144) {
    int i = tid - 128;
    float xi = (float)i;
    float acc[NHEAD] = {0.f,0.f,0.f,0.f,0.f,0.f};
    for (int d = 0; d < DIMC; ++d) {
      float r = fmaxf(fmaf(xi, h_w1[d], h_b1[d]), 0.f);
      #pragma unroll
      for (int h = 0; h < NHEAD; ++h) acc[h] = fmaf(r, h_w2[h*DIMC + d], acc[h]);
    }
    #pragma unroll
    for (int h = 0; h < NHEAD; ++h) tblh[i][h] = acc[h] + h_b2[h];
  }
  __syncthreads();
  for (int i = tid; i < NHEAD*625; i += 256) {
    int h = i / 625, e = i - h*625;
    bias_h[i] = tblh[hop[e]][h];
  }
}

// ---------------------------------------------------------------------------
// LayerNorm: one wave per row (216 cols -> lane, lane+64, lane+128, lane+192)
// ---------------------------------------------------------------------------
__global__ __launch_bounds__(256) void ln_kernel(
    const float* __restrict__ x, const float* __restrict__ w,
    const float* __restrict__ b, float* __restrict__ out)
{
  int lane = threadIdx.x & 63;
  int row  = blockIdx.x * 4 + (threadIdx.x >> 6);
  const float* xr = x + (size_t)row * DIMC;
  float v0 = xr[lane];
  float v1 = xr[lane + 64];
  float v2 = xr[lane + 128];
  float v3 = (lane < 24) ? xr[lane + 192] : 0.f;
  float s1 = v0 + v1 + v2 + v3;
  float s2 = v0*v0 + v1*v1 + v2*v2 + v3*v3;
  #pragma unroll
  for (int m = 32; m; m >>= 1) { s1 += __shfl_xor(s1, m); s2 += __shfl_xor(s2, m); }
  float mu  = s1 * (1.f/216.f);
  float var = fmaxf(s2 * (1.f/216.f) - mu*mu, 0.f);
  float rs  = rsqrtf(var + 1e-5f);
  float* orow = out + (size_t)row * DIMC;
  orow[lane]       = (v0-mu)*rs*w[lane]       + b[lane];
  orow[lane+64]    = (v1-mu)*rs*w[lane+64]    + b[lane+64];
  orow[lane+128]   = (v2-mu)*rs*w[lane+128]   + b[lane+128];
  if (lane < 24)
    orow[lane+192] = (v3-mu)*rs*w[lane+192]   + b[lane+192];
}

// ---------------------------------------------------------------------------
// Generic tiled GEMM:  C[M,N] = epi( A[M,K] @ B[N,K]^T )
// BM=BN=64, BK=8, 256 threads, 4x4 microtile, fp32 accumulate.
// ---------------------------------------------------------------------------
enum { EPI_QKV = 0, EPI_PROJ = 1, EPI_FC1 = 2, EPI_FC2 = 3 };

__device__ __forceinline__ float lda_(const float* p){ return *p; }
__device__ __forceinline__ float lda_(const bf16* p){ return __bfloat162float(*p); }

template<typename TA, int EPI>
__global__ __launch_bounds__(256) void gemm_kernel(
    const TA* __restrict__ A, const float* __restrict__ B,
    const float* __restrict__ bias, const void* __restrict__ res,
    void* __restrict__ out, int N, int K)
{
  __shared__ __align__(16) float As[8][68];
  __shared__ __align__(16) float Bs[8][68];
  int row0 = blockIdx.x * 64;
  int col0 = blockIdx.y * 64;
  int tid = threadIdx.x;
  int tx = tid & 15, ty = tid >> 4;
  int kk_s = tid & 7, m_s = tid >> 3;
  float acc[4][4] = {};

  for (int k0 = 0; k0 < K; k0 += 8) {
    float a0 = lda_(A + (size_t)(row0 + m_s)      * K + k0 + kk_s);
    float a1 = lda_(A + (size_t)(row0 + m_s + 32) * K + k0 + kk_s);
    int c0 = col0 + m_s, c1 = col0 + m_s + 32;
    float b0 = (c0 < N) ? B[(size_t)c0 * K + k0 + kk_s] : 0.f;
    float b1 = (c1 < N) ? B[(size_t)c1 * K + k0 + kk_s] : 0.f;
    As[kk_s][m_s]      = a0;
    As[kk_s][m_s + 32] = a1;
    Bs[kk_s][m_s]      = b0;
    Bs[kk_s][m_s + 32] = b1;
    __syncthreads();
    #pragma unroll
    for (int kk = 0; kk < 8; ++kk) {
      float4 av = *(const float4*)&As[kk][ty*4];
      float4 bv = *(const float4*)&Bs[kk][tx*4];
      float a[4] = {av.x, av.y, av.z, av.w};
      float bb[4] = {bv.x, bv.y, bv.z, bv.w};
      #pragma unroll
      for (int i = 0; i < 4; ++i)
        #pragma unroll
        for (int j = 0; j < 4; ++j)
          acc[i][j] = fmaf(a[i], bb[j], acc[i][j]);
    }
    __syncthreads();
  }

  #pragma unroll
  for (int i = 0; i < 4; ++i) {
    int r = row0 + ty*4 + i;
    #pragma unroll
    for (int j = 0; j < 4; ++j) {
      int c = col0 + tx*4 + j;
      if (c >= N) continue;
      float v = acc[i][j];
      if constexpr (EPI == EPI_QKV) {
        // out base = v-buffer; layout in ws is [v][q][k] contiguous.
        int s = c / DIMC, rem = c - s*DIMC;
        int hh = rem / HDIM, d = rem - hh*HDIM;
        int n = r / TLEN, t = r - n*TLEN;
        int sel = s + 1; if (sel == 3) sel = 0;   // q->1, k->2, v->0
        ((float*)out)[(size_t)sel*BUF_ELEMS +
                      ((size_t)(n*NHEAD + hh)*TLEN + t)*HDIM + d] = v;
      } else if constexpr (EPI == EPI_PROJ) {
        v += bias[c] + ((const float*)res)[(size_t)r*DIMC + c];
        ((float*)out)[(size_t)r*DIMC + c] = v;
      } else if constexpr (EPI == EPI_FC1) {
        v += bias[c];
        v = v * 0.5f * (1.f + erff(v * 0.70710678118654752f));   // exact GELU
        ((bf16*)out)[(size_t)r*864 + c] = __float2bfloat16(v);
      } else { // EPI_FC2
        v += bias[c] + ((const float*)res)[(size_t)r*DIMC + c];
        ((float*)out)[(size_t)r*DIMC + c] = v;
      }
    }
  }
}

// ---------------------------------------------------------------------------
// Flash attention, fp32: block = 64 queries (one (n,h)), 256 threads,
// thread = (query, k-group of 4).  K/V tiles of 64 rows staged in LDS.
// ---------------------------------------------------------------------------
__global__ __launch_bounds__(256) void attn_kernel(
    const float* __restrict__ qb, const float* __restrict__ kb,
    const float* __restrict__ vb, const float* __restrict__ bias_t,
    const float* __restrict__ bias_h, float* __restrict__ o)
{
  __shared__ __align__(16) float Ks[64][36];
  __shared__ __align__(16) float Vs[64][36];
  __shared__ float bh[625];
  __shared__ float bt[127];

  int nh = blockIdx.y;                 // 0..47
  int head = nh % NHEAD;
  int n = nh / NHEAD;
  int tid = threadIdx.x;

  for (int i = tid; i < 625; i += 256) bh[i] = bias_h[head*625 + i];
  for (int i = tid; i < 127; i += 256) bt[i] = bias_t[head*127 + i];

  int qi = tid >> 2, g = tid & 3;
  int tq = blockIdx.x * 64 + qi;
  int vq = tq % 25, fq = tq / 25;

  const float* qp = qb + ((size_t)nh * TLEN + tq) * HDIM;
  float4 q4[9];
  #pragma unroll
  for (int j = 0; j < 9; ++j) q4[j] = *(const float4*)(qp + j*4);

  float m = -1e30f, l = 0.f;
  float4 o4[9];
  #pragma unroll
  for (int j = 0; j < 9; ++j) o4[j] = make_float4(0.f,0.f,0.f,0.f);

  const float* kbase = kb + (size_t)nh * TLEN * HDIM;
  const float* vbase = vb + (size_t)nh * TLEN * HDIM;

  int vk = g, fk = 0;
  for (int t0 = 0; t0 < TLEN; t0 += 64) {
    __syncthreads();
    for (int idx = tid; idx < 576; idx += 256) {
      int r = idx / 9, c = idx - r*9;
      *(float4*)&Ks[r][c*4] = *(const float4*)(kbase + (size_t)(t0 + r)*HDIM + c*4);
      *(float4*)&Vs[r][c*4] = *(const float4*)(vbase + (size_t)(t0 + r)*HDIM + c*4);
    }
    __syncthreads();

    for (int i = 0; i < 16; ++i) {
      int kk = i*4 + g;
      float s = 0.f;
      #pragma unroll
      for (int j = 0; j < 9; ++j) {
        float4 kv = *(const float4*)&Ks[kk][j*4];
        s = fmaf(q4[j].x, kv.x, s);
        s = fmaf(q4[j].y, kv.y, s);
        s = fmaf(q4[j].z, kv.z, s);
        s = fmaf(q4[j].w, kv.w, s);
      }
      s = (s + bh[vq*25 + vk] + bt[fq - fk + 63]) * QK_SCALE;
      float p;
      if (s > m) {
        float cc = __expf(m - s);
        m = s; l *= cc;
        #pragma unroll
        for (int j = 0; j < 9; ++j) {
          o4[j].x *= cc; o4[j].y *= cc; o4[j].z *= cc; o4[j].w *= cc;
        }
        p = 1.f;
      } else {
        p = __expf(s - m);
      }
      l += p;
      #pragma unroll
      for (int j = 0; j < 9; ++j) {
        float4 vv = *(const float4*)&Vs[kk][j*4];
        o4[j].x = fmaf(p, vv.x, o4[j].x);
        o4[j].y = fmaf(p, vv.y, o4[j].y);
        o4[j].z = fmaf(p, vv.z, o4[j].z);
        o4[j].w = fmaf(p, vv.w, o4[j].w);
      }
      vk += 4; if (vk >= 25) { vk -= 25; ++fk; }
    }
  }

  // merge the 4 k-groups (lanes qi*4 .. qi*4+3, same wave)
  #pragma unroll
  for (int mask = 1; mask <= 2; mask <<= 1) {
    float mo = __shfl_xor(m, mask);
    float lo = __shfl_xor(l, mask);
    float mn = fmaxf(m, mo);
    float ea = __expf(m - mn), eb = __expf(mo - mn);
    l = l*ea + lo*eb;
    #pragma unroll
    for (int j = 0; j < 9; ++j) {
      float ox = __shfl_xor(o4[j].x, mask);
      float oy = __shfl_xor(o4[j].y, mask);
      float oz = __shfl_xor(o4[j].z, mask);
      float ow = __shfl_xor(o4[j].w, mask);
      o4[j].x = o4[j].x*ea + ox*eb;
      o4[j].y = o4[j].y*ea + oy*eb;
      o4[j].z = o4[j].z*ea + oz*eb;
      o4[j].w = o4[j].w*ea + ow*eb;
    }
    m = mn;
  }

  if (g == 0) {
    float inv = 1.f / l;
    float* op = o + ((size_t)n*TLEN + tq)*DIMC + head*HDIM;
    #pragma unroll
    for (int j = 0; j < 9; ++j) {
      float4 t = o4[j];
      t.x *= inv; t.y *= inv; t.z *= inv; t.w *= inv;
      *(float4*)(op + j*4) = t;
    }
  }
}

// ---------------------------------------------------------------------------
extern "C" void kernel_launch(void* const* d_in, const int* in_sizes, int n_in,
                              void* d_out, int out_size, void* d_ws, size_t ws_size,
                              hipStream_t stream) {
  const float* x      = (const float*)d_in[0];
  const float* qkv_w  = (const float*)d_in[1];
  const float* proj_w = (const float*)d_in[2];
  const float* proj_b = (const float*)d_in[3];
  const float* norm_w = (const float*)d_in[4];
  const float* norm_b = (const float*)d_in[5];
  const float* norm1_w= (const float*)d_in[6];
  const float* norm1_b= (const float*)d_in[7];
  const float* fc1_w  = (const float*)d_in[8];
  const float* fc1_b  = (const float*)d_in[9];
  const float* fc2_w  = (const float*)d_in[10];
  const float* fc2_b  = (const float*)d_in[11];
  const float* t_w1   = (const float*)d_in[12];
  const float* t_b1   = (const float*)d_in[13];
  const float* t_w2   = (const float*)d_in[14];
  const float* t_b2   = (const float*)d_in[15];
  const float* h_w1   = (const float*)d_in[16];
  const float* h_b1   = (const float*)d_in[17];
  const float* h_w2   = (const float*)d_in[18];
  const float* h_b2   = (const float*)d_in[19];
  const int*   hop    = (const int*)d_in[20];

  // workspace arena (bytes):
  //   [0        , 11059200)  h (LN out)      -> later attn output o
  //   [11059200 , 22118400)  v
  //   [22118400 , 33177600)  q               -> later x1 (fp32)
  //   [33177600 , 44236800)  k               -> later h1 (fp32)
  //   [0        , 22118400)  g bf16 (fc1 out) overlaps dead o+v
  //   [44236800 , ...)       bias tables
  const size_t WS_NEED = 44236800u + 4u*(127u*6u + 625u*6u);
  if (ws_size < WS_NEED) return;

  char* ws = (char*)d_ws;
  float* h_buf = (float*)(ws + 0);
  float* v_buf = (float*)(ws + 11059200);
  float* q_buf = (float*)(ws + 22118400);
  float* k_buf = (float*)(ws + 33177600);
  bf16*  g_buf = (bf16*) (ws + 0);
  float* bt    = (float*)(ws + 44236800);
  float* bh    = bt + 127*6;

  bias_tables_kernel<<<1, 256, 0, stream>>>(t_w1, t_b1, t_w2, t_b2,
                                            h_w1, h_b1, h_w2, h_b2,
                                            hop, bt, bh);

  ln_kernel<<<MROWS/4, 256, 0, stream>>>(x, norm_w, norm_b, h_buf);

  // qkv: A = h (fp32), scatter into [v][q][k] starting at v_buf
  gemm_kernel<float, EPI_QKV><<<dim3(MROWS/64, 11), 256, 0, stream>>>(
      h_buf, qkv_w, nullptr, nullptr, v_buf, 648, DIMC);

  attn_kernel<<<dim3(TLEN/64, NBATCH*NHEAD), 256, 0, stream>>>(
      q_buf, k_buf, v_buf, bt, bh, h_buf);   // o -> h_buf (h is dead)

  // x1 = x + o @ proj_w^T + proj_b   (fp32, into q_buf)
  gemm_kernel<float, EPI_PROJ><<<dim3(MROWS/64, 4), 256, 0, stream>>>(
      h_buf, proj_w, proj_b, x, q_buf, DIMC, DIMC);

  ln_kernel<<<MROWS/4, 256, 0, stream>>>(q_buf, norm1_w, norm1_b, k_buf);

  // g = gelu(h1 @ fc1^T + b1)  (bf16, overlaps dead o+v)
  gemm_kernel<float, EPI_FC1><<<dim3(MROWS/64, 14), 256, 0, stream>>>(
      k_buf, fc1_w, fc1_b, nullptr, g_buf, 864, DIMC);

  // out = x1 + g @ fc2^T + b2  (fp32 to d_out)
  gemm_kernel<bf16, EPI_FC2><<<dim3(MROWS/64, 4), 256, 0, stream>>>(
      g_buf, fc2_w, fc2_b, q_buf, d_out, DIMC, 864);
}

// Round 3
// 470.756 us; speedup vs baseline: 1.5832x; 1.5832x over previous
//
#include <hip/hip_runtime.h>
#include <hip/hip_bf16.h>

// Round 2: bf16 MFMA flash attention; SIMT fp32 GEMMs unchanged.
// N=8, T=1600 (F=64 x V=25), DIM=216, H=6, HD=36.

#define NHEAD  6
#define TLEN   1600
#define DIMC   216
#define HDIM   36
#define NBATCH 8
#define MROWS  12800
#define QK_SCALE (1.f/6.f)

typedef __attribute__((ext_vector_type(8))) short s16x8;
typedef __attribute__((ext_vector_type(4))) float f32x4;

#define MFMA16(a,b,c) __builtin_amdgcn_mfma_f32_16x16x32_bf16((a),(b),(c),0,0,0)

__device__ __forceinline__ float  bf2f(ushort u){ return __uint_as_float((uint)u << 16); }
__device__ __forceinline__ ushort f2bf(float f){
  uint u = __float_as_uint(f);
  u += 0x7FFFu + ((u >> 16) & 1u);      // RNE
  return (ushort)(u >> 16);
}

// ---------------------------------------------------------------------------
// Bias tables: bias_t[6][127], bias_h[6][625]
// ---------------------------------------------------------------------------
__global__ __launch_bounds__(256) void bias_tables_kernel(
    const float* __restrict__ t_w1, const float* __restrict__ t_b1,
    const float* __restrict__ t_w2, const float* __restrict__ t_b2,
    const float* __restrict__ h_w1, const float* __restrict__ h_b1,
    const float* __restrict__ h_w2, const float* __restrict__ h_b2,
    const int*  __restrict__ hop,
    float* __restrict__ bias_t, float* __restrict__ bias_h)
{
  __shared__ float tblh[16][NHEAD];
  int tid = threadIdx.x;
  if (tid < 127) {
    float xi = (float)(tid - 63);
    float acc[NHEAD] = {0.f,0.f,0.f,0.f,0.f,0.f};
    for (int d = 0; d < DIMC; ++d) {
      float r = fmaxf(fmaf(xi, t_w1[d], t_b1[d]), 0.f);
      #pragma unroll
      for (int h = 0; h < NHEAD; ++h) acc[h] = fmaf(r, t_w2[h*DIMC + d], acc[h]);
    }
    #pragma unroll
    for (int h = 0; h < NHEAD; ++h) bias_t[h*127 + tid] = acc[h] + t_b2[h];
  }
  if (tid >= 128 && tid < 144) {
    int i = tid - 128;
    float xi = (float)i;
    float acc[NHEAD] = {0.f,0.f,0.f,0.f,0.f,0.f};
    for (int d = 0; d < DIMC; ++d) {
      float r = fmaxf(fmaf(xi, h_w1[d], h_b1[d]), 0.f);
      #pragma unroll
      for (int h = 0; h < NHEAD; ++h) acc[h] = fmaf(r, h_w2[h*DIMC + d], acc[h]);
    }
    #pragma unroll
    for (int h = 0; h < NHEAD; ++h) tblh[i][h] = acc[h] + h_b2[h];
  }
  __syncthreads();
  for (int i = tid; i < NHEAD*625; i += 256) {
    int h = i / 625, e = i - h*625;
    bias_h[i] = tblh[hop[e]][h];
  }
}

// ---------------------------------------------------------------------------
// LayerNorm: one wave per row; TO = float or ushort(bf16)
// ---------------------------------------------------------------------------
__device__ __forceinline__ void sto_(float*  p, float v){ *p = v; }
__device__ __forceinline__ void sto_(ushort* p, float v){ *p = f2bf(v); }

template<typename TO>
__global__ __launch_bounds__(256) void ln_kernel(
    const float* __restrict__ x, const float* __restrict__ w,
    const float* __restrict__ b, TO* __restrict__ out)
{
  int lane = threadIdx.x & 63;
  int row  = blockIdx.x * 4 + (threadIdx.x >> 6);
  const float* xr = x + (size_t)row * DIMC;
  float v0 = xr[lane];
  float v1 = xr[lane + 64];
  float v2 = xr[lane + 128];
  float v3 = (lane < 24) ? xr[lane + 192] : 0.f;
  float s1 = v0 + v1 + v2 + v3;
  float s2 = v0*v0 + v1*v1 + v2*v2 + v3*v3;
  #pragma unroll
  for (int m = 32; m; m >>= 1) { s1 += __shfl_xor(s1, m); s2 += __shfl_xor(s2, m); }
  float mu  = s1 * (1.f/216.f);
  float var = fmaxf(s2 * (1.f/216.f) - mu*mu, 0.f);
  float rs  = rsqrtf(var + 1e-5f);
  TO* orow = out + (size_t)row * DIMC;
  sto_(orow + lane,       (v0-mu)*rs*w[lane]       + b[lane]);
  sto_(orow + lane + 64,  (v1-mu)*rs*w[lane+64]    + b[lane+64]);
  sto_(orow + lane + 128, (v2-mu)*rs*w[lane+128]   + b[lane+128]);
  if (lane < 24)
    sto_(orow + lane + 192, (v3-mu)*rs*w[lane+192] + b[lane+192]);
}

// ---------------------------------------------------------------------------
// SIMT tiled GEMM:  C[M,N] = epi( A[M,K] @ B[N,K]^T ), fp32 accumulate
// ---------------------------------------------------------------------------
enum { EPI_QKV = 0, EPI_PROJ = 1, EPI_FC1 = 2, EPI_FC2 = 3 };

__device__ __forceinline__ float lda_(const float*  p){ return *p; }
__device__ __forceinline__ float lda_(const ushort* p){ return bf2f(*p); }

template<typename TA, int EPI>
__global__ __launch_bounds__(256) void gemm_kernel(
    const TA* __restrict__ A, const float* __restrict__ B,
    const float* __restrict__ bias, const void* __restrict__ res,
    void* __restrict__ out, int N, int K)
{
  __shared__ __align__(16) float As[8][68];
  __shared__ __align__(16) float Bs[8][68];
  int row0 = blockIdx.x * 64;
  int col0 = blockIdx.y * 64;
  int tid = threadIdx.x;
  int tx = tid & 15, ty = tid >> 4;
  int kk_s = tid & 7, m_s = tid >> 3;
  float acc[4][4] = {};

  for (int k0 = 0; k0 < K; k0 += 8) {
    float a0 = lda_(A + (size_t)(row0 + m_s)      * K + k0 + kk_s);
    float a1 = lda_(A + (size_t)(row0 + m_s + 32) * K + k0 + kk_s);
    int c0 = col0 + m_s, c1 = col0 + m_s + 32;
    float b0 = (c0 < N) ? B[(size_t)c0 * K + k0 + kk_s] : 0.f;
    float b1 = (c1 < N) ? B[(size_t)c1 * K + k0 + kk_s] : 0.f;
    As[kk_s][m_s]      = a0;
    As[kk_s][m_s + 32] = a1;
    Bs[kk_s][m_s]      = b0;
    Bs[kk_s][m_s + 32] = b1;
    __syncthreads();
    #pragma unroll
    for (int kk = 0; kk < 8; ++kk) {
      float4 av = *(const float4*)&As[kk][ty*4];
      float4 bv = *(const float4*)&Bs[kk][tx*4];
      float a[4] = {av.x, av.y, av.z, av.w};
      float bb[4] = {bv.x, bv.y, bv.z, bv.w};
      #pragma unroll
      for (int i = 0; i < 4; ++i)
        #pragma unroll
        for (int j = 0; j < 4; ++j)
          acc[i][j] = fmaf(a[i], bb[j], acc[i][j]);
    }
    __syncthreads();
  }

  #pragma unroll
  for (int i = 0; i < 4; ++i) {
    int r = row0 + ty*4 + i;
    #pragma unroll
    for (int j = 0; j < 4; ++j) {
      int c = col0 + tx*4 + j;
      if (c >= N) continue;
      float v = acc[i][j];
      if constexpr (EPI == EPI_QKV) {
        // bf16 outputs: q padded [nh][t][64], k padded [nh][t][64], v^T [nh][d][t]
        int s = c / DIMC, rem = c - s*DIMC;
        int hh = rem / HDIM, d = rem - hh*HDIM;
        int n = r / TLEN, t = r - n*TLEN;
        int nh = n*NHEAD + hh;
        ushort bv16 = f2bf(v);
        ushort* qb = (ushort*)out;
        if (s == 0)      qb[(((size_t)nh*TLEN + t) << 6) + d] = bv16;
        else if (s == 1) qb[4915200u + (((size_t)nh*TLEN + t) << 6) + d] = bv16;
        else             qb[9830400u + ((size_t)nh*HDIM + d)*TLEN + t] = bv16;
      } else if constexpr (EPI == EPI_PROJ) {
        v += bias[c] + ((const float*)res)[(size_t)r*DIMC + c];
        ((float*)out)[(size_t)r*DIMC + c] = v;
      } else if constexpr (EPI == EPI_FC1) {
        v += bias[c];
        v = v * 0.5f * (1.f + erff(v * 0.70710678118654752f));
        ((ushort*)out)[(size_t)r*864 + c] = f2bf(v);
      } else { // EPI_FC2
        v += bias[c] + ((const float*)res)[(size_t)r*DIMC + c];
        ((float*)out)[(size_t)r*DIMC + c] = v;
      }
    }
  }
}

// ---------------------------------------------------------------------------
// MFMA flash attention: block = 64 queries of one (n,h), 4 waves x 16 q.
// KV tiles of 64; K LDS [64][72] (d padded to 64), V^T LDS [48][72],
// per-wave P LDS [16][72].  16x16x32 bf16 MFMA, fp32 accum.
// ---------------------------------------------------------------------------
__global__ __launch_bounds__(256) void attn_kernel(
    const ushort* __restrict__ qb, const ushort* __restrict__ kb,
    const ushort* __restrict__ vb, const float* __restrict__ bias_t,
    const float* __restrict__ bias_h, ushort* __restrict__ o)
{
  __shared__ ushort Ks[64][72];
  __shared__ ushort Vt[48][72];
  __shared__ ushort Ps[4][16][72];
  __shared__ float bh_s[625];
  __shared__ float bt_s[127];

  int tid  = threadIdx.x;
  int nh   = blockIdx.y;
  int head = nh % NHEAD, n = nh / NHEAD;
  int wave = tid >> 6, lane = tid & 63;
  int g = lane >> 4, l15 = lane & 15;

  for (int i = tid; i < 625; i += 256) bh_s[i] = bias_h[head*625 + i];
  for (int i = tid; i < 127; i += 256) bt_s[i] = bias_t[head*127 + i];
  for (int i = tid; i < 432; i += 256) ((uint*)&Vt[36][0])[i] = 0;  // V^T pad rows

  // Q fragments (A operand): row = lane&15 of this wave's 16-q tile
  int qtok = blockIdx.x*64 + wave*16 + l15;
  const ushort* qrow = qb + (((size_t)nh*TLEN + qtok) << 6);
  s16x8 qf0 = *(const s16x8*)(qrow + g*8);
  s16x8 qf1 = *(const s16x8*)(qrow + 32 + g*8);

  // this lane's 4 accumulator q-rows: q = base + 4g + r
  int vq[4], fq[4];
  #pragma unroll
  for (int r = 0; r < 4; ++r) {
    int qt = blockIdx.x*64 + wave*16 + 4*g + r;
    fq[r] = qt / 25; vq[r] = qt - fq[r]*25;
  }
  // this lane's 4 k-columns per tile: k = t0 + kt*16 + l15
  int vk[4], fk[4];
  #pragma unroll
  for (int kt = 0; kt < 4; ++kt) {
    int k0 = kt*16 + l15;
    int f = (k0 >= 50) ? 2 : (k0 >= 25 ? 1 : 0);
    fk[kt] = f; vk[kt] = k0 - f*25;
  }

  float m[4]    = {-1e30f,-1e30f,-1e30f,-1e30f};
  float lsum[4] = {0.f,0.f,0.f,0.f};
  f32x4 oa[3];
  #pragma unroll
  for (int dt = 0; dt < 3; ++dt) oa[dt] = (f32x4){0.f,0.f,0.f,0.f};

  for (int t0 = 0; t0 < TLEN; t0 += 64) {
    __syncthreads();                       // previous tile's LDS reads done
    #pragma unroll
    for (int it = 0; it < 2; ++it) {       // K tile: 64 rows x 64 cols (padded src)
      int idx = tid + it*256;
      int rr = idx >> 3, cc = idx & 7;
      *(s16x8*)&Ks[rr][cc*8] =
          *(const s16x8*)(kb + (((size_t)nh*TLEN + t0 + rr) << 6) + cc*8);
    }
    for (int idx = tid; idx < 288; idx += 256) {   // V^T tile: 36 rows x 64 cols
      int dd = idx >> 3, cc = idx & 7;
      *(s16x8*)&Vt[dd][cc*8] =
          *(const s16x8*)(vb + ((size_t)nh*HDIM + dd)*TLEN + t0 + cc*8);
    }
    __syncthreads();

    // QK^T: 4 k-tiles x 2 k-steps
    f32x4 sa[4];
    #pragma unroll
    for (int kt = 0; kt < 4; ++kt) {
      f32x4 z = {0.f,0.f,0.f,0.f};
      const ushort* kr = &Ks[kt*16 + l15][g*8];
      z = MFMA16(qf0, *(const s16x8*)kr, z);
      z = MFMA16(qf1, *(const s16x8*)(kr + 32), z);
      sa[kt] = z;
    }

    // bias + online softmax
    float p[4][4], mt[4];
    #pragma unroll
    for (int r = 0; r < 4; ++r) {
      #pragma unroll
      for (int kt = 0; kt < 4; ++kt)
        p[r][kt] = (sa[kt][r] + bh_s[vq[r]*25 + vk[kt]]
                              + bt_s[fq[r] - fk[kt] + 63]) * QK_SCALE;
      mt[r] = fmaxf(fmaxf(p[r][0], p[r][1]), fmaxf(p[r][2], p[r][3]));
    }
    #pragma unroll
    for (int mask = 1; mask <= 8; mask <<= 1) {
      #pragma unroll
      for (int r = 0; r < 4; ++r) mt[r] = fmaxf(mt[r], __shfl_xor(mt[r], mask));
    }
    float fac[4], ls[4];
    #pragma unroll
    for (int r = 0; r < 4; ++r) {
      float mn = fmaxf(m[r], mt[r]);
      fac[r] = __expf(m[r] - mn);
      m[r] = mn;
      float s0 = __expf(p[r][0] - mn), s1 = __expf(p[r][1] - mn);
      float s2 = __expf(p[r][2] - mn), s3 = __expf(p[r][3] - mn);
      Ps[wave][4*g + r][l15]      = f2bf(s0);
      Ps[wave][4*g + r][l15 + 16] = f2bf(s1);
      Ps[wave][4*g + r][l15 + 32] = f2bf(s2);
      Ps[wave][4*g + r][l15 + 48] = f2bf(s3);
      ls[r] = (s0 + s1) + (s2 + s3);
    }
    #pragma unroll
    for (int mask = 1; mask <= 8; mask <<= 1) {
      #pragma unroll
      for (int r = 0; r < 4; ++r) ls[r] += __shfl_xor(ls[r], mask);
    }
    #pragma unroll
    for (int r = 0; r < 4; ++r) lsum[r] = lsum[r]*fac[r] + ls[r];
    #pragma unroll
    for (int dt = 0; dt < 3; ++dt) {
      #pragma unroll
      for (int r = 0; r < 4; ++r) oa[dt][r] *= fac[r];
    }

    asm volatile("s_waitcnt lgkmcnt(0)" ::: "memory");  // P writes visible (same wave)

    // PV: O += P @ V   (A=P, B=V^T rows)
    #pragma unroll
    for (int ks = 0; ks < 2; ++ks) {
      s16x8 pf = *(const s16x8*)&Ps[wave][l15][ks*32 + g*8];
      #pragma unroll
      for (int dt = 0; dt < 3; ++dt)
        oa[dt] = MFMA16(pf, *(const s16x8*)&Vt[dt*16 + l15][ks*32 + g*8], oa[dt]);
    }

    // advance k indices by 64 (= 2*25 + 14)
    #pragma unroll
    for (int kt = 0; kt < 4; ++kt) {
      vk[kt] += 14; fk[kt] += 2;
      if (vk[kt] >= 25) { vk[kt] -= 25; fk[kt] += 1; }
    }
  }

  float inv[4];
  #pragma unroll
  for (int r = 0; r < 4; ++r) inv[r] = 1.f / lsum[r];
  #pragma unroll
  for (int dt = 0; dt < 3; ++dt) {
    int d = dt*16 + l15;
    if (d < HDIM) {
      #pragma unroll
      for (int r = 0; r < 4; ++r) {
        int t = blockIdx.x*64 + wave*16 + 4*g + r;
        o[((size_t)(n*TLEN + t))*DIMC + head*HDIM + d] = f2bf(oa[dt][r]*inv[r]);
      }
    }
  }
}

// ---------------------------------------------------------------------------
extern "C" void kernel_launch(void* const* d_in, const int* in_sizes, int n_in,
                              void* d_out, int out_size, void* d_ws, size_t ws_size,
                              hipStream_t stream) {
  const float* x      = (const float*)d_in[0];
  const float* qkv_w  = (const float*)d_in[1];
  const float* proj_w = (const float*)d_in[2];
  const float* proj_b = (const float*)d_in[3];
  const float* norm_w = (const float*)d_in[4];
  const float* norm_b = (const float*)d_in[5];
  const float* norm1_w= (const float*)d_in[6];
  const float* norm1_b= (const float*)d_in[7];
  const float* fc1_w  = (const float*)d_in[8];
  const float* fc1_b  = (const float*)d_in[9];
  const float* fc2_w  = (const float*)d_in[10];
  const float* fc2_b  = (const float*)d_in[11];
  const float* t_w1   = (const float*)d_in[12];
  const float* t_b1   = (const float*)d_in[13];
  const float* t_w2   = (const float*)d_in[14];
  const float* t_b2   = (const float*)d_in[15];
  const float* h_w1   = (const float*)d_in[16];
  const float* h_b1   = (const float*)d_in[17];
  const float* h_w2   = (const float*)d_in[18];
  const float* h_b2   = (const float*)d_in[19];
  const int*   hop    = (const int*)d_in[20];

  // workspace (bytes):
  //  [0,        11059200)  h fp32 (LN1)     -> later o bf16 [0, 5529600)
  //  [11059200, 20889600)  q bf16 padded [48][1600][64]
  //  [20889600, 30720000)  k bf16 padded
  //  [30720000, 36249600)  v^T bf16 [48][36][1600]
  //  [ 5529600, 16588800)  x1 fp32          (over dead q head; after attn)
  //  [16588800, 22118400)  h1 bf16          (over dead q/k)
  //  [22118400, 44236800)  g bf16 [12800][864]  (over dead k tail + v)
  //  [44236800, ...)       bias tables
  const size_t WS_NEED = 44236800u + 4u*(127u*6u + 625u*6u);
  if (ws_size < WS_NEED) return;

  char* ws = (char*)d_ws;
  float*  h_buf = (float*) (ws);
  ushort* qkv_b = (ushort*)(ws + 11059200);
  ushort* o_buf = (ushort*)(ws);
  float*  x1    = (float*) (ws + 5529600);
  ushort* h1    = (ushort*)(ws + 16588800);
  ushort* g_buf = (ushort*)(ws + 22118400);
  float*  bt    = (float*) (ws + 44236800);
  float*  bh    = bt + 127*6;

  // zero q/k pad columns (d 36..63) once per call
  hipMemsetAsync(ws + 11059200, 0, 19660800, stream);

  bias_tables_kernel<<<1, 256, 0, stream>>>(t_w1, t_b1, t_w2, t_b2,
                                            h_w1, h_b1, h_w2, h_b2, hop, bt, bh);

  ln_kernel<float><<<MROWS/4, 256, 0, stream>>>(x, norm_w, norm_b, h_buf);

  gemm_kernel<float, EPI_QKV><<<dim3(MROWS/64, 11), 256, 0, stream>>>(
      h_buf, qkv_w, nullptr, nullptr, qkv_b, 648, DIMC);

  attn_kernel<<<dim3(TLEN/64, NBATCH*NHEAD), 256, 0, stream>>>(
      qkv_b, qkv_b + 4915200u, qkv_b + 9830400u, bt, bh, o_buf);

  gemm_kernel<ushort, EPI_PROJ><<<dim3(MROWS/64, 4), 256, 0, stream>>>(
      o_buf, proj_w, proj_b, x, x1, DIMC, DIMC);

  ln_kernel<ushort><<<MROWS/4, 256, 0, stream>>>(x1, norm1_w, norm1_b, h1);

  gemm_kernel<ushort, EPI_FC1><<<dim3(MROWS/64, 14), 256, 0, stream>>>(
      h1, fc1_w, fc1_b, nullptr, g_buf, 864, DIMC);

  gemm_kernel<ushort, EPI_FC2><<<dim3(MROWS/64, 4), 256, 0, stream>>>(
      g_buf, fc2_w, fc2_b, x1, d_out, DIMC, 864);
}

// Round 4
// 263.369 us; speedup vs baseline: 2.8299x; 1.7874x over previous
//
#include <hip/hip_runtime.h>
#include <hip/hip_bf16.h>

// Round 3: bf16 MFMA everywhere (4 GEMMs + flash attention).
// N=8, T=1600 (F=64 x V=25), DIM=216, H=6, HD=36.

#define NHEAD  6
#define TLEN   1600
#define DIMC   216
#define HDIM   36
#define NBATCH 8
#define MROWS  12800
#define QK_SCALE (1.f/6.f)

typedef __attribute__((ext_vector_type(8))) short s16x8;
typedef __attribute__((ext_vector_type(4))) float f32x4;

#define MFMA16(a,b,c) __builtin_amdgcn_mfma_f32_16x16x32_bf16((a),(b),(c),0,0,0)

__device__ __forceinline__ float  bf2f(ushort u){ return __uint_as_float((uint)u << 16); }
__device__ __forceinline__ ushort f2bf(float f){
  uint u = __float_as_uint(f);
  u += 0x7FFFu + ((u >> 16) & 1u);      // RNE
  return (ushort)(u >> 16);
}

__device__ __forceinline__ void glds16(const ushort* g, ushort* l){
  __builtin_amdgcn_global_load_lds(
      (const __attribute__((address_space(1))) void*)g,
      (__attribute__((address_space(3))) void*)l, 16, 0, 0);
}

// ---------------------------------------------------------------------------
// Bias tables: bias_t[6][127], bias_h[6][625]
// ---------------------------------------------------------------------------
__global__ __launch_bounds__(256) void bias_tables_kernel(
    const float* __restrict__ t_w1, const float* __restrict__ t_b1,
    const float* __restrict__ t_w2, const float* __restrict__ t_b2,
    const float* __restrict__ h_w1, const float* __restrict__ h_b1,
    const float* __restrict__ h_w2, const float* __restrict__ h_b2,
    const int*  __restrict__ hop,
    float* __restrict__ bias_t, float* __restrict__ bias_h)
{
  __shared__ float tblh[16][NHEAD];
  int tid = threadIdx.x;
  if (tid < 127) {
    float xi = (float)(tid - 63);
    float acc[NHEAD] = {0.f,0.f,0.f,0.f,0.f,0.f};
    for (int d = 0; d < DIMC; ++d) {
      float r = fmaxf(fmaf(xi, t_w1[d], t_b1[d]), 0.f);
      #pragma unroll
      for (int h = 0; h < NHEAD; ++h) acc[h] = fmaf(r, t_w2[h*DIMC + d], acc[h]);
    }
    #pragma unroll
    for (int h = 0; h < NHEAD; ++h) bias_t[h*127 + tid] = acc[h] + t_b2[h];
  }
  if (tid >= 128 && tid < 144) {
    int i = tid - 128;
    float xi = (float)i;
    float acc[NHEAD] = {0.f,0.f,0.f,0.f,0.f,0.f};
    for (int d = 0; d < DIMC; ++d) {
      float r = fmaxf(fmaf(xi, h_w1[d], h_b1[d]), 0.f);
      #pragma unroll
      for (int h = 0; h < NHEAD; ++h) acc[h] = fmaf(r, h_w2[h*DIMC + d], acc[h]);
    }
    #pragma unroll
    for (int h = 0; h < NHEAD; ++h) tblh[i][h] = acc[h] + h_b2[h];
  }
  __syncthreads();
  for (int i = tid; i < NHEAD*625; i += 256) {
    int h = i / 625, e = i - h*625;
    bias_h[i] = tblh[hop[e]][h];
  }
}

// ---------------------------------------------------------------------------
// Weight convert+pad: fp32 [N][K] -> bf16 [Npad][Kpad] (zeros in pad)
// ---------------------------------------------------------------------------
__global__ __launch_bounds__(256) void convpad_kernel(
    const float* __restrict__ src, ushort* __restrict__ dst,
    int N, int K, int Kpad, int total)
{
  int idx = blockIdx.x*256 + threadIdx.x;
  if (idx >= total) return;
  int n = idx / Kpad, k = idx - n*Kpad;
  float v = (n < N && k < K) ? src[n*K + k] : 0.f;
  dst[idx] = f2bf(v);
}

// ---------------------------------------------------------------------------
// LayerNorm: fp32 in (stride 216) -> bf16 out (stride 224, cols 216..223 = 0)
// ---------------------------------------------------------------------------
__global__ __launch_bounds__(256) void ln_kernel(
    const float* __restrict__ x, const float* __restrict__ w,
    const float* __restrict__ b, ushort* __restrict__ out)
{
  int lane = threadIdx.x & 63;
  int row  = blockIdx.x * 4 + (threadIdx.x >> 6);
  const float* xr = x + (size_t)row * DIMC;
  float v0 = xr[lane];
  float v1 = xr[lane + 64];
  float v2 = xr[lane + 128];
  float v3 = (lane < 24) ? xr[lane + 192] : 0.f;
  float s1 = v0 + v1 + v2 + v3;
  float s2 = v0*v0 + v1*v1 + v2*v2 + v3*v3;
  #pragma unroll
  for (int m = 32; m; m >>= 1) { s1 += __shfl_xor(s1, m); s2 += __shfl_xor(s2, m); }
  float mu  = s1 * (1.f/216.f);
  float var = fmaxf(s2 * (1.f/216.f) - mu*mu, 0.f);
  float rs  = rsqrtf(var + 1e-5f);
  ushort* orow = out + (size_t)row * 224;
  orow[lane]       = f2bf((v0-mu)*rs*w[lane]       + b[lane]);
  orow[lane+64]    = f2bf((v1-mu)*rs*w[lane+64]    + b[lane+64]);
  orow[lane+128]   = f2bf((v2-mu)*rs*w[lane+128]   + b[lane+128]);
  if (lane < 32) {
    float vv = (lane < 24) ? (v3-mu)*rs*w[lane+192] + b[lane+192] : 0.f;
    orow[lane+192] = f2bf(vv);
  }
}

// ---------------------------------------------------------------------------
// MFMA GEMM: C[M,N] = epi( A[M,K]bf16 @ B[Npad,K]bf16^T ), fp32 accum.
// BM = WM*4 (4 waves, wave owns WM rows x 64 cols), BN=64, BK=32.
// LDS fragment-blocked layout, global_load_lds width-16 staging, dbuf.
// ---------------------------------------------------------------------------
enum { EPI_QKV = 0, EPI_PROJ = 1, EPI_FC1 = 2, EPI_FC2 = 3 };

template<int EPI, int WM>
__global__ __launch_bounds__(256) void gemm_mfma(
    const ushort* __restrict__ A, const ushort* __restrict__ B,
    const float* __restrict__ bias, const float* __restrict__ res,
    float* __restrict__ outf, ushort* __restrict__ oq,
    ushort* __restrict__ ok, ushort* __restrict__ ov,
    int N, int K)
{
  constexpr int BM = WM*4;
  constexpr int NMF = WM/16;           // m-frags per wave
  constexpr int APASS = (BM*4)/256;    // A chunk passes (chunks = BM*4)
  __shared__ ushort As[2][BM*32];
  __shared__ ushort Bs[2][64*32];

  int tid = threadIdx.x;
  int w = tid >> 6, lane = tid & 63, l15 = lane & 15, g = lane >> 4;
  int row0 = blockIdx.x*BM, col0 = blockIdx.y*64;
  const int NT = K >> 5;

  f32x4 acc[NMF][4];
  #pragma unroll
  for (int i = 0; i < NMF; ++i)
    #pragma unroll
    for (int nf = 0; nf < 4; ++nf) acc[i][nf] = (f32x4){0.f,0.f,0.f,0.f};

  // ---- stage tile t into buffer buf ----
  #define STAGE(buf, t)                                                       \
  {                                                                           \
    int k0 = (t) << 5;                                                        \
    _Pragma("unroll")                                                         \
    for (int p = 0; p < APASS; ++p) {                                         \
      int idx = p*256 + tid;                                                  \
      int mf = idx >> 6, kq = (idx >> 4) & 3, r = idx & 15;                   \
      glds16(A + (size_t)(row0 + mf*16 + r)*K + k0 + kq*8,                    \
             &As[buf][(p*256 + w*64)*8]);                                     \
    }                                                                         \
    {                                                                         \
      int kq = (tid >> 4) & 3, r = tid & 15;                                  \
      glds16(B + (size_t)(col0 + w*16 + r)*K + k0 + kq*8,                     \
             &Bs[buf][w*512]);                                                \
    }                                                                         \
  }

  STAGE(0, 0)
  __syncthreads();

  for (int t = 0; t < NT; ++t) {
    int buf = t & 1;
    if (t + 1 < NT) STAGE(buf ^ 1, t + 1)
    #pragma unroll
    for (int i = 0; i < NMF; ++i) {
      s16x8 a = *(const s16x8*)&As[buf][((w*NMF + i)*64 + g*16 + l15)*8];
      #pragma unroll
      for (int nf = 0; nf < 4; ++nf) {
        s16x8 b = *(const s16x8*)&Bs[buf][(nf*64 + g*16 + l15)*8];
        acc[i][nf] = MFMA16(a, b, acc[i][nf]);
      }
    }
    __syncthreads();
  }
  #undef STAGE

  // ---- epilogue ----
  #pragma unroll
  for (int i = 0; i < NMF; ++i) {
    #pragma unroll
    for (int nf = 0; nf < 4; ++nf) {
      int c = col0 + nf*16 + l15;
      if (c >= N) continue;
      #pragma unroll
      for (int r = 0; r < 4; ++r) {
        int rr = row0 + w*WM + i*16 + 4*g + r;
        float v = acc[i][nf][r];
        if constexpr (EPI == EPI_QKV) {
          int s = c / DIMC, rem = c - s*DIMC;
          int hh = rem / HDIM, d = rem - hh*HDIM;
          int n = rr / TLEN, t = rr - n*TLEN;
          int nh = n*NHEAD + hh;
          ushort bv = f2bf(v);
          if (s == 0)      oq[(((size_t)nh*TLEN + t) << 6) + d] = bv;
          else if (s == 1) ok[(((size_t)nh*TLEN + t) << 6) + d] = bv;
          else             ov[((size_t)nh*HDIM + d)*TLEN + t] = bv;
        } else if constexpr (EPI == EPI_PROJ) {
          outf[(size_t)rr*DIMC + c] = v + bias[c] + res[(size_t)rr*DIMC + c];
        } else if constexpr (EPI == EPI_FC1) {
          v += bias[c];
          v = v * 0.5f * (1.f + erff(v * 0.70710678118654752f));
          oq[(size_t)rr*864 + c] = f2bf(v);
        } else { // EPI_FC2
          outf[(size_t)rr*DIMC + c] = v + bias[c] + res[(size_t)rr*DIMC + c];
        }
      }
    }
  }
}

// ---------------------------------------------------------------------------
// MFMA flash attention (unchanged from round 2 except o stride 224)
// ---------------------------------------------------------------------------
__global__ __launch_bounds__(256) void attn_kernel(
    const ushort* __restrict__ qb, const ushort* __restrict__ kb,
    const ushort* __restrict__ vb, const float* __restrict__ bias_t,
    const float* __restrict__ bias_h, ushort* __restrict__ o)
{
  __shared__ ushort Ks[64][72];
  __shared__ ushort Vt[48][72];
  __shared__ ushort Ps[4][16][72];
  __shared__ float bh_s[625];
  __shared__ float bt_s[127];

  int tid  = threadIdx.x;
  int nh   = blockIdx.y;
  int head = nh % NHEAD, n = nh / NHEAD;
  int wave = tid >> 6, lane = tid & 63;
  int g = lane >> 4, l15 = lane & 15;

  for (int i = tid; i < 625; i += 256) bh_s[i] = bias_h[head*625 + i];
  for (int i = tid; i < 127; i += 256) bt_s[i] = bias_t[head*127 + i];
  for (int i = tid; i < 432; i += 256) ((uint*)&Vt[36][0])[i] = 0;

  int qtok = blockIdx.x*64 + wave*16 + l15;
  const ushort* qrow = qb + (((size_t)nh*TLEN + qtok) << 6);
  s16x8 qf0 = *(const s16x8*)(qrow + g*8);
  s16x8 qf1 = *(const s16x8*)(qrow + 32 + g*8);

  int vq[4], fq[4];
  #pragma unroll
  for (int r = 0; r < 4; ++r) {
    int qt = blockIdx.x*64 + wave*16 + 4*g + r;
    fq[r] = qt / 25; vq[r] = qt - fq[r]*25;
  }
  int vk[4], fk[4];
  #pragma unroll
  for (int kt = 0; kt < 4; ++kt) {
    int k0 = kt*16 + l15;
    int f = (k0 >= 50) ? 2 : (k0 >= 25 ? 1 : 0);
    fk[kt] = f; vk[kt] = k0 - f*25;
  }

  float m[4]    = {-1e30f,-1e30f,-1e30f,-1e30f};
  float lsum[4] = {0.f,0.f,0.f,0.f};
  f32x4 oa[3];
  #pragma unroll
  for (int dt = 0; dt < 3; ++dt) oa[dt] = (f32x4){0.f,0.f,0.f,0.f};

  for (int t0 = 0; t0 < TLEN; t0 += 64) {
    __syncthreads();
    #pragma unroll
    for (int it = 0; it < 2; ++it) {
      int idx = tid + it*256;
      int rr = idx >> 3, cc = idx & 7;
      *(s16x8*)&Ks[rr][cc*8] =
          *(const s16x8*)(kb + (((size_t)nh*TLEN + t0 + rr) << 6) + cc*8);
    }
    for (int idx = tid; idx < 288; idx += 256) {
      int dd = idx >> 3, cc = idx & 7;
      *(s16x8*)&Vt[dd][cc*8] =
          *(const s16x8*)(vb + ((size_t)nh*HDIM + dd)*TLEN + t0 + cc*8);
    }
    __syncthreads();

    f32x4 sa[4];
    #pragma unroll
    for (int kt = 0; kt < 4; ++kt) {
      f32x4 z = {0.f,0.f,0.f,0.f};
      const ushort* kr = &Ks[kt*16 + l15][g*8];
      z = MFMA16(qf0, *(const s16x8*)kr, z);
      z = MFMA16(qf1, *(const s16x8*)(kr + 32), z);
      sa[kt] = z;
    }

    float p[4][4], mt[4];
    #pragma unroll
    for (int r = 0; r < 4; ++r) {
      #pragma unroll
      for (int kt = 0; kt < 4; ++kt)
        p[r][kt] = (sa[kt][r] + bh_s[vq[r]*25 + vk[kt]]
                              + bt_s[fq[r] - fk[kt] + 63]) * QK_SCALE;
      mt[r] = fmaxf(fmaxf(p[r][0], p[r][1]), fmaxf(p[r][2], p[r][3]));
    }
    #pragma unroll
    for (int mask = 1; mask <= 8; mask <<= 1) {
      #pragma unroll
      for (int r = 0; r < 4; ++r) mt[r] = fmaxf(mt[r], __shfl_xor(mt[r], mask));
    }
    float fac[4], ls[4];
    #pragma unroll
    for (int r = 0; r < 4; ++r) {
      float mn = fmaxf(m[r], mt[r]);
      fac[r] = __expf(m[r] - mn);
      m[r] = mn;
      float s0 = __expf(p[r][0] - mn), s1 = __expf(p[r][1] - mn);
      float s2 = __expf(p[r][2] - mn), s3 = __expf(p[r][3] - mn);
      Ps[wave][4*g + r][l15]      = f2bf(s0);
      Ps[wave][4*g + r][l15 + 16] = f2bf(s1);
      Ps[wave][4*g + r][l15 + 32] = f2bf(s2);
      Ps[wave][4*g + r][l15 + 48] = f2bf(s3);
      ls[r] = (s0 + s1) + (s2 + s3);
    }
    #pragma unroll
    for (int mask = 1; mask <= 8; mask <<= 1) {
      #pragma unroll
      for (int r = 0; r < 4; ++r) ls[r] += __shfl_xor(ls[r], mask);
    }
    #pragma unroll
    for (int r = 0; r < 4; ++r) lsum[r] = lsum[r]*fac[r] + ls[r];
    #pragma unroll
    for (int dt = 0; dt < 3; ++dt) {
      #pragma unroll
      for (int r = 0; r < 4; ++r) oa[dt][r] *= fac[r];
    }

    asm volatile("s_waitcnt lgkmcnt(0)" ::: "memory");

    #pragma unroll
    for (int ks = 0; ks < 2; ++ks) {
      s16x8 pf = *(const s16x8*)&Ps[wave][l15][ks*32 + g*8];
      #pragma unroll
      for (int dt = 0; dt < 3; ++dt)
        oa[dt] = MFMA16(pf, *(const s16x8*)&Vt[dt*16 + l15][ks*32 + g*8], oa[dt]);
    }

    #pragma unroll
    for (int kt = 0; kt < 4; ++kt) {
      vk[kt] += 14; fk[kt] += 2;
      if (vk[kt] >= 25) { vk[kt] -= 25; fk[kt] += 1; }
    }
  }

  float inv[4];
  #pragma unroll
  for (int r = 0; r < 4; ++r) inv[r] = 1.f / lsum[r];
  #pragma unroll
  for (int dt = 0; dt < 3; ++dt) {
    int d = dt*16 + l15;
    if (d < HDIM) {
      #pragma unroll
      for (int r = 0; r < 4; ++r) {
        int t = blockIdx.x*64 + wave*16 + 4*g + r;
        o[((size_t)(n*TLEN + t))*224 + head*HDIM + d] = f2bf(oa[dt][r]*inv[r]);
      }
    }
  }
}

// ---------------------------------------------------------------------------
extern "C" void kernel_launch(void* const* d_in, const int* in_sizes, int n_in,
                              void* d_out, int out_size, void* d_ws, size_t ws_size,
                              hipStream_t stream) {
  const float* x      = (const float*)d_in[0];
  const float* qkv_w  = (const float*)d_in[1];
  const float* proj_w = (const float*)d_in[2];
  const float* proj_b = (const float*)d_in[3];
  const float* norm_w = (const float*)d_in[4];
  const float* norm_b = (const float*)d_in[5];
  const float* norm1_w= (const float*)d_in[6];
  const float* norm1_b= (const float*)d_in[7];
  const float* fc1_w  = (const float*)d_in[8];
  const float* fc1_b  = (const float*)d_in[9];
  const float* fc2_w  = (const float*)d_in[10];
  const float* fc2_b  = (const float*)d_in[11];
  const float* t_w1   = (const float*)d_in[12];
  const float* t_b1   = (const float*)d_in[13];
  const float* t_w2   = (const float*)d_in[14];
  const float* t_b2   = (const float*)d_in[15];
  const float* h_w1   = (const float*)d_in[16];
  const float* h_b1   = (const float*)d_in[17];
  const float* h_w2   = (const float*)d_in[18];
  const float* h_b2   = (const float*)d_in[19];
  const int*   hop    = (const int*)d_in[20];

  // workspace (bytes):
  //  [0,        5734400)   h bf16 [12800][224]      (dead after qkv)
  //  [5734400,  15564800)  q bf16 [48][1600][64]    (dead after attn)
  //  [15564800, 25395200)  k bf16                   (dead after attn)
  //  [25395200, 30924800)  vT bf16 [48][36][1600]   (dead after attn)
  //  [30924800, 36659200)  o bf16 [12800][224]      (dead after proj)
  //  [0,        11059200)  x1 fp32 (over dead h+q)
  //  [11468800, 17203200)  h1 bf16 (over dead q/k)
  //  [17203200, 39321600)  g bf16 [12800][864] (over dead k/v/o)
  //  [39321600, ...)       padded bf16 weights, bias tables
  const size_t WS_NEED = 40613504u;
  if (ws_size < WS_NEED) return;

  char* ws = (char*)d_ws;
  ushort* h_bf   = (ushort*)(ws);
  ushort* q_bf   = (ushort*)(ws + 5734400);
  ushort* k_bf   = (ushort*)(ws + 15564800);
  ushort* v_bf   = (ushort*)(ws + 25395200);
  ushort* o_bf   = (ushort*)(ws + 30924800);
  float*  x1     = (float*) (ws);
  ushort* h1_bf  = (ushort*)(ws + 11468800);
  ushort* g_bf   = (ushort*)(ws + 17203200);
  ushort* qkv_wb = (ushort*)(ws + 39321600);
  ushort* proj_wb= (ushort*)(ws + 39636992);
  ushort* fc1_wb = (ushort*)(ws + 39751680);
  ushort* fc2_wb = (ushort*)(ws + 40153088);
  float*  bt     = (float*) (ws + 40595456);
  float*  bh     = bt + 127*6;

  // zero q/k pad cols (d 36..63) and o pad cols (216..223)
  hipMemsetAsync(ws + 5734400, 0, 19660800, stream);
  hipMemsetAsync(ws + 30924800, 0, 5734400, stream);

  bias_tables_kernel<<<1, 256, 0, stream>>>(t_w1, t_b1, t_w2, t_b2,
                                            h_w1, h_b1, h_w2, h_b2, hop, bt, bh);

  convpad_kernel<<<(704*224+255)/256, 256, 0, stream>>>(qkv_w,  qkv_wb, 648, 216, 224, 704*224);
  convpad_kernel<<<(256*224+255)/256, 256, 0, stream>>>(proj_w, proj_wb,216, 216, 224, 256*224);
  convpad_kernel<<<(896*224+255)/256, 256, 0, stream>>>(fc1_w,  fc1_wb, 864, 216, 224, 896*224);
  convpad_kernel<<<(256*864+255)/256, 256, 0, stream>>>(fc2_w,  fc2_wb, 216, 864, 864, 256*864);

  ln_kernel<<<MROWS/4, 256, 0, stream>>>(x, norm_w, norm_b, h_bf);

  gemm_mfma<EPI_QKV, 32><<<dim3(MROWS/128, 11), 256, 0, stream>>>(
      h_bf, qkv_wb, nullptr, nullptr, nullptr, q_bf, k_bf, v_bf, 648, 224);

  attn_kernel<<<dim3(TLEN/64, NBATCH*NHEAD), 256, 0, stream>>>(
      q_bf, k_bf, v_bf, bt, bh, o_bf);

  gemm_mfma<EPI_PROJ, 16><<<dim3(MROWS/64, 4), 256, 0, stream>>>(
      o_bf, proj_wb, proj_b, x, x1, nullptr, nullptr, nullptr, 216, 224);

  ln_kernel<<<MROWS/4, 256, 0, stream>>>(x1, norm1_w, norm1_b, h1_bf);

  gemm_mfma<EPI_FC1, 32><<<dim3(MROWS/128, 14), 256, 0, stream>>>(
      h1_bf, fc1_wb, fc1_b, nullptr, nullptr, g_bf, nullptr, nullptr, 864, 224);

  gemm_mfma<EPI_FC2, 16><<<dim3(MROWS/64, 4), 256, 0, stream>>>(
      g_bf, fc2_wb, fc2_b, x1, (float*)d_out, nullptr, nullptr, nullptr, 216, 864);
}

// Round 5
// 200.679 us; speedup vs baseline: 3.7139x; 1.3124x over previous
//
#include <hip/hip_runtime.h>
#include <hip/hip_bf16.h>

// Round 4: lane-local MFMA flash attention (swapped QK / swapped PV),
// bf16 MFMA GEMMs as round 3.  N=8, T=1600 (F=64 x V=25), DIM=216, H=6, HD=36.

#define NHEAD  6
#define TLEN   1600
#define DIMC   216
#define HDIM   36
#define NBATCH 8
#define MROWS  12800
#define QK_SCALE (1.f/6.f)

typedef __attribute__((ext_vector_type(8))) short s16x8;
typedef __attribute__((ext_vector_type(4))) float f32x4;

#define MFMA16(a,b,c) __builtin_amdgcn_mfma_f32_16x16x32_bf16((a),(b),(c),0,0,0)

__device__ __forceinline__ float  bf2f(ushort u){ return __uint_as_float((uint)u << 16); }
__device__ __forceinline__ ushort f2bf(float f){
  uint u = __float_as_uint(f);
  u += 0x7FFFu + ((u >> 16) & 1u);      // RNE
  return (ushort)(u >> 16);
}
__device__ __forceinline__ uint cvtpk_bf16(float lo, float hi){
  uint r;
  asm("v_cvt_pk_bf16_f32 %0, %1, %2" : "=v"(r) : "v"(lo), "v"(hi));
  return r;
}
__device__ __forceinline__ void glds16(const ushort* g, ushort* l){
  __builtin_amdgcn_global_load_lds(
      (const __attribute__((address_space(1))) void*)g,
      (__attribute__((address_space(3))) void*)l, 16, 0, 0);
}

// ---------------------------------------------------------------------------
// Bias tables, PRE-SCALED by 1/6: bias_t[6][127], bias_h[6][625]
// ---------------------------------------------------------------------------
__global__ __launch_bounds__(256) void bias_tables_kernel(
    const float* __restrict__ t_w1, const float* __restrict__ t_b1,
    const float* __restrict__ t_w2, const float* __restrict__ t_b2,
    const float* __restrict__ h_w1, const float* __restrict__ h_b1,
    const float* __restrict__ h_w2, const float* __restrict__ h_b2,
    const int*  __restrict__ hop,
    float* __restrict__ bias_t, float* __restrict__ bias_h)
{
  __shared__ float tblh[16][NHEAD];
  int tid = threadIdx.x;
  if (tid < 127) {
    float xi = (float)(tid - 63);
    float acc[NHEAD] = {0.f,0.f,0.f,0.f,0.f,0.f};
    for (int d = 0; d < DIMC; ++d) {
      float r = fmaxf(fmaf(xi, t_w1[d], t_b1[d]), 0.f);
      #pragma unroll
      for (int h = 0; h < NHEAD; ++h) acc[h] = fmaf(r, t_w2[h*DIMC + d], acc[h]);
    }
    #pragma unroll
    for (int h = 0; h < NHEAD; ++h)
      bias_t[h*127 + tid] = (acc[h] + t_b2[h]) * QK_SCALE;
  }
  if (tid >= 128 && tid < 144) {
    int i = tid - 128;
    float xi = (float)i;
    float acc[NHEAD] = {0.f,0.f,0.f,0.f,0.f,0.f};
    for (int d = 0; d < DIMC; ++d) {
      float r = fmaxf(fmaf(xi, h_w1[d], h_b1[d]), 0.f);
      #pragma unroll
      for (int h = 0; h < NHEAD; ++h) acc[h] = fmaf(r, h_w2[h*DIMC + d], acc[h]);
    }
    #pragma unroll
    for (int h = 0; h < NHEAD; ++h) tblh[i][h] = (acc[h] + h_b2[h]) * QK_SCALE;
  }
  __syncthreads();
  for (int i = tid; i < NHEAD*625; i += 256) {
    int h = i / 625, e = i - h*625;
    bias_h[i] = tblh[hop[e]][h];
  }
}

// ---------------------------------------------------------------------------
// Weight convert+pad: fp32 [N][K] -> bf16 [Npad][Kpad] (zeros in pad)
// ---------------------------------------------------------------------------
__global__ __launch_bounds__(256) void convpad_kernel(
    const float* __restrict__ src, ushort* __restrict__ dst,
    int N, int K, int Kpad, int total)
{
  int idx = blockIdx.x*256 + threadIdx.x;
  if (idx >= total) return;
  int n = idx / Kpad, k = idx - n*Kpad;
  float v = (n < N && k < K) ? src[n*K + k] : 0.f;
  dst[idx] = f2bf(v);
}

// ---------------------------------------------------------------------------
// LayerNorm: fp32 in (stride 216) -> bf16 out (stride 224, cols 216..223 = 0)
// ---------------------------------------------------------------------------
__global__ __launch_bounds__(256) void ln_kernel(
    const float* __restrict__ x, const float* __restrict__ w,
    const float* __restrict__ b, ushort* __restrict__ out)
{
  int lane = threadIdx.x & 63;
  int row  = blockIdx.x * 4 + (threadIdx.x >> 6);
  const float* xr = x + (size_t)row * DIMC;
  float v0 = xr[lane];
  float v1 = xr[lane + 64];
  float v2 = xr[lane + 128];
  float v3 = (lane < 24) ? xr[lane + 192] : 0.f;
  float s1 = v0 + v1 + v2 + v3;
  float s2 = v0*v0 + v1*v1 + v2*v2 + v3*v3;
  #pragma unroll
  for (int m = 32; m; m >>= 1) { s1 += __shfl_xor(s1, m); s2 += __shfl_xor(s2, m); }
  float mu  = s1 * (1.f/216.f);
  float var = fmaxf(s2 * (1.f/216.f) - mu*mu, 0.f);
  float rs  = rsqrtf(var + 1e-5f);
  ushort* orow = out + (size_t)row * 224;
  orow[lane]       = f2bf((v0-mu)*rs*w[lane]       + b[lane]);
  orow[lane+64]    = f2bf((v1-mu)*rs*w[lane+64]    + b[lane+64]);
  orow[lane+128]   = f2bf((v2-mu)*rs*w[lane+128]   + b[lane+128]);
  if (lane < 32) {
    float vv = (lane < 24) ? (v3-mu)*rs*w[lane+192] + b[lane+192] : 0.f;
    orow[lane+192] = f2bf(vv);
  }
}

// ---------------------------------------------------------------------------
// MFMA GEMM (unchanged from round 3)
// ---------------------------------------------------------------------------
enum { EPI_QKV = 0, EPI_PROJ = 1, EPI_FC1 = 2, EPI_FC2 = 3 };

template<int EPI, int WM>
__global__ __launch_bounds__(256) void gemm_mfma(
    const ushort* __restrict__ A, const ushort* __restrict__ B,
    const float* __restrict__ bias, const float* __restrict__ res,
    float* __restrict__ outf, ushort* __restrict__ oq,
    ushort* __restrict__ ok, ushort* __restrict__ ov,
    int N, int K)
{
  constexpr int BM = WM*4;
  constexpr int NMF = WM/16;
  constexpr int APASS = (BM*4)/256;
  __shared__ ushort As[2][BM*32];
  __shared__ ushort Bs[2][64*32];

  int tid = threadIdx.x;
  int w = tid >> 6, lane = tid & 63, l15 = lane & 15, g = lane >> 4;
  int row0 = blockIdx.x*BM, col0 = blockIdx.y*64;
  const int NT = K >> 5;

  f32x4 acc[NMF][4];
  #pragma unroll
  for (int i = 0; i < NMF; ++i)
    #pragma unroll
    for (int nf = 0; nf < 4; ++nf) acc[i][nf] = (f32x4){0.f,0.f,0.f,0.f};

  #define STAGE(buf, t)                                                       \
  {                                                                           \
    int k0 = (t) << 5;                                                        \
    _Pragma("unroll")                                                         \
    for (int p = 0; p < APASS; ++p) {                                         \
      int idx = p*256 + tid;                                                  \
      int mf = idx >> 6, kq = (idx >> 4) & 3, r = idx & 15;                   \
      glds16(A + (size_t)(row0 + mf*16 + r)*K + k0 + kq*8,                    \
             &As[buf][(p*256 + w*64)*8]);                                     \
    }                                                                         \
    {                                                                         \
      int kq = (tid >> 4) & 3, r = tid & 15;                                  \
      glds16(B + (size_t)(col0 + w*16 + r)*K + k0 + kq*8,                     \
             &Bs[buf][w*512]);                                                \
    }                                                                         \
  }

  STAGE(0, 0)
  __syncthreads();

  for (int t = 0; t < NT; ++t) {
    int buf = t & 1;
    if (t + 1 < NT) STAGE(buf ^ 1, t + 1)
    #pragma unroll
    for (int i = 0; i < NMF; ++i) {
      s16x8 a = *(const s16x8*)&As[buf][((w*NMF + i)*64 + g*16 + l15)*8];
      #pragma unroll
      for (int nf = 0; nf < 4; ++nf) {
        s16x8 b = *(const s16x8*)&Bs[buf][(nf*64 + g*16 + l15)*8];
        acc[i][nf] = MFMA16(a, b, acc[i][nf]);
      }
    }
    __syncthreads();
  }
  #undef STAGE

  #pragma unroll
  for (int i = 0; i < NMF; ++i) {
    #pragma unroll
    for (int nf = 0; nf < 4; ++nf) {
      int c = col0 + nf*16 + l15;
      if (c >= N) continue;
      #pragma unroll
      for (int r = 0; r < 4; ++r) {
        int rr = row0 + w*WM + i*16 + 4*g + r;
        float v = acc[i][nf][r];
        if constexpr (EPI == EPI_QKV) {
          int s = c / DIMC, rem = c - s*DIMC;
          int hh = rem / HDIM, d = rem - hh*HDIM;
          int n = rr / TLEN, t = rr - n*TLEN;
          int nh = n*NHEAD + hh;
          ushort bv = f2bf(v);
          if (s == 0)      oq[(((size_t)nh*TLEN + t) << 6) + d] = bv;
          else if (s == 1) ok[(((size_t)nh*TLEN + t) << 6) + d] = bv;
          else             ov[((size_t)nh*HDIM + d)*TLEN + t] = bv;
        } else if constexpr (EPI == EPI_PROJ) {
          outf[(size_t)rr*DIMC + c] = v + bias[c] + res[(size_t)rr*DIMC + c];
        } else if constexpr (EPI == EPI_FC1) {
          v += bias[c];
          v = v * 0.5f * (1.f + erff(v * 0.70710678118654752f));
          oq[(size_t)rr*864 + c] = f2bf(v);
        } else {
          outf[(size_t)rr*DIMC + c] = v + bias[c] + res[(size_t)rr*DIMC + c];
        }
      }
    }
  }
}

// ---------------------------------------------------------------------------
// Lane-local MFMA flash attention.
// Block = 64 queries of one (n,h), 4 waves x 16 q (q = lane&15 per wave).
// S^T = mfma(K, Q): lane owns 16 scores (k = kt*16+4g+r) for q = l15.
// O^T = mfma(V^T, P^T): V^T staged with k-slot permutation so P^T fragment
// is the lane's own cvt_pk'd values.  No P LDS, in-lane softmax state.
// K staged via global_load_lds into linear [64][64] with XOR-swizzled source.
// ---------------------------------------------------------------------------
__global__ __launch_bounds__(256) void attn_kernel(
    const ushort* __restrict__ qb, const ushort* __restrict__ kb,
    const ushort* __restrict__ vb, const float* __restrict__ bias_t,
    const float* __restrict__ bias_h, ushort* __restrict__ o)
{
  __shared__ ushort Ks[64*64];        // [row][granule^((row&7))] 16B granules
  __shared__ ushort Vt[48][72];       // rows d, cols = permuted k-slots
  __shared__ float bh_s[625];
  __shared__ float bt_s[127];

  int tid = threadIdx.x;
  // XCD-aware decode: bid&7 = XCD, each XCD owns 6 heads (K/V L2-resident)
  int bid = blockIdx.x;
  int c   = bid >> 3;
  int nh  = (bid & 7)*6 + c/25;
  int qt  = c - (c/25)*25;
  int head = nh % NHEAD, n = nh / NHEAD;
  int wave = tid >> 6, lane = tid & 63;
  int g = lane >> 4, l15 = lane & 15, l7 = l15 & 7;

  for (int i = tid; i < 625; i += 256) bh_s[i] = bias_h[head*625 + i];
  for (int i = tid; i < 127; i += 256) bt_s[i] = bias_t[head*127 + i];
  for (int i = tid; i < 432; i += 256) ((uint*)&Vt[36][0])[i] = 0;  // pad d-rows

  // Q fragment (B operand): per-lane Q[q=l15][d = 32s + g*8 + j]
  int qglob = qt*64 + wave*16 + l15;
  const ushort* qrow = qb + (((size_t)nh*TLEN + qglob) << 6);
  s16x8 qf0 = *(const s16x8*)(qrow + g*8);
  s16x8 qf1 = *(const s16x8*)(qrow + 32 + g*8);

  // per-lane softmax constants: q fixed
  int fq  = qglob / 25;
  int vq25 = (qglob - fq*25) * 25;

  // per-lane key index state: k = t0 + kt*16 + 4g + r
  int vkb[4], ftb[4];
  #pragma unroll
  for (int kt = 0; kt < 4; ++kt) {
    int k0 = kt*16 + 4*g;
    int f0 = (k0 >= 50) ? 2 : (k0 >= 25 ? 1 : 0);
    vkb[kt] = k0 - f0*25;
    ftb[kt] = fq - f0 + 63;
  }

  float m = -1e30f, lsum = 0.f;
  f32x4 oa[3];
  #pragma unroll
  for (int dt = 0; dt < 3; ++dt) oa[dt] = (f32x4){0.f,0.f,0.f,0.f};

  const ushort* kbase = kb + ((size_t)nh*TLEN << 6);
  const ushort* vbase = vb + (size_t)nh*HDIM*TLEN;

  for (int t0 = 0; t0 < TLEN; t0 += 64) {
    __syncthreads();
    // ---- stage K: 512 16B granules, XOR-swizzled source (linear LDS dest)
    #pragma unroll
    for (int p = 0; p < 2; ++p) {
      int gid = p*256 + tid;
      int row = gid >> 3, grl = gid & 7;
      int grd = grl ^ (row & 7);
      glds16(kbase + (((size_t)(t0 + row)) << 6) + grd*8,
             &Ks[(p*256 + wave*64)*8]);
    }
    // ---- stage V^T with k-slot permutation: slot 8g'+4kt_rel+r <- key 16kt_rel+4g'+r
    for (int idx = tid; idx < 576; idx += 256) {
      int d = idx >> 4, rest = idx & 15;
      int ks = rest >> 3, kg = rest & 7;
      int sg = ((kg & 3) << 1) + (kg >> 2);
      ushort4 vv = *(const ushort4*)(vbase + (size_t)d*TLEN + t0 + ks*32 + kg*4);
      *(ushort4*)&Vt[d][ks*32 + sg*4] = vv;
    }
    __syncthreads();

    // ---- QK^T (swapped): sa[kt][r] = S[k = kt*16+4g+r][q = l15]
    f32x4 sa[4];
    #pragma unroll
    for (int kt = 0; kt < 4; ++kt) {
      int row = kt*16 + l15;
      s16x8 a0 = *(const s16x8*)&Ks[(row << 6) + ((g ^ l7) << 3)];
      s16x8 a1 = *(const s16x8*)&Ks[(row << 6) + (((g + 4) ^ l7) << 3)];
      f32x4 z = (f32x4){0.f,0.f,0.f,0.f};
      z = MFMA16(a0, qf0, z);
      sa[kt] = MFMA16(a1, qf1, z);
    }

    // ---- bias + in-lane online softmax (q = l15 fixed)
    float mt = -1e30f;
    #pragma unroll
    for (int kt = 0; kt < 4; ++kt) {
      float bt0 = bt_s[ftb[kt]];
      float bt1 = bt_s[ftb[kt] - 1];
      #pragma unroll
      for (int r = 0; r < 4; ++r) {
        int vkr = vkb[kt] + r;
        bool wrap = vkr >= 25;
        float bsum = bh_s[vq25 + (wrap ? vkr - 25 : vkr)] + (wrap ? bt1 : bt0);
        float p = fmaf(sa[kt][r], QK_SCALE, bsum);
        sa[kt][r] = p;
        mt = fmaxf(mt, p);
      }
    }
    mt = fmaxf(mt, __shfl_xor(mt, 16));
    mt = fmaxf(mt, __shfl_xor(mt, 32));
    float mn = fmaxf(m, mt);
    float fac = __expf(m - mn);
    m = mn;
    float ls = 0.f;
    #pragma unroll
    for (int kt = 0; kt < 4; ++kt) {
      #pragma unroll
      for (int r = 0; r < 4; ++r) {
        float e = __expf(sa[kt][r] - mn);
        sa[kt][r] = e;
        ls += e;
      }
    }
    ls += __shfl_xor(ls, 16);
    ls += __shfl_xor(ls, 32);
    lsum = lsum*fac + ls;
    #pragma unroll
    for (int dt = 0; dt < 3; ++dt) {
      #pragma unroll
      for (int r = 0; r < 4; ++r) oa[dt][r] *= fac;
    }

    // ---- PV (swapped): O^T += V^T @ P^T, P^T frag = lane's own values
    #pragma unroll
    for (int ks = 0; ks < 2; ++ks) {
      union { s16x8 v; uint u[4]; } pf;
      pf.u[0] = cvtpk_bf16(sa[2*ks][0],   sa[2*ks][1]);
      pf.u[1] = cvtpk_bf16(sa[2*ks][2],   sa[2*ks][3]);
      pf.u[2] = cvtpk_bf16(sa[2*ks+1][0], sa[2*ks+1][1]);
      pf.u[3] = cvtpk_bf16(sa[2*ks+1][2], sa[2*ks+1][3]);
      #pragma unroll
      for (int dt = 0; dt < 3; ++dt) {
        s16x8 a = *(const s16x8*)&Vt[dt*16 + l15][ks*32 + g*8];
        oa[dt] = MFMA16(a, pf.v, oa[dt]);
      }
    }

    // ---- advance key indices by 64 (= 2*25 + 14)
    #pragma unroll
    for (int kt = 0; kt < 4; ++kt) {
      vkb[kt] += 14; ftb[kt] -= 2;
      if (vkb[kt] >= 25) { vkb[kt] -= 25; ftb[kt] -= 1; }
    }
  }

  // ---- normalize + store: lane holds O^T[d = dt*16+4g+r][q = l15]
  float inv = 1.f / lsum;
  ushort* orow = o + ((size_t)(n*TLEN + qglob))*224 + head*HDIM;
  #pragma unroll
  for (int dt = 0; dt < 3; ++dt) {
    if (dt < 2 || g == 0) {
      ushort4 st;
      st.x = f2bf(oa[dt][0]*inv);
      st.y = f2bf(oa[dt][1]*inv);
      st.z = f2bf(oa[dt][2]*inv);
      st.w = f2bf(oa[dt][3]*inv);
      *(ushort4*)(orow + dt*16 + 4*g) = st;
    }
  }
}

// ---------------------------------------------------------------------------
extern "C" void kernel_launch(void* const* d_in, const int* in_sizes, int n_in,
                              void* d_out, int out_size, void* d_ws, size_t ws_size,
                              hipStream_t stream) {
  const float* x      = (const float*)d_in[0];
  const float* qkv_w  = (const float*)d_in[1];
  const float* proj_w = (const float*)d_in[2];
  const float* proj_b = (const float*)d_in[3];
  const float* norm_w = (const float*)d_in[4];
  const float* norm_b = (const float*)d_in[5];
  const float* norm1_w= (const float*)d_in[6];
  const float* norm1_b= (const float*)d_in[7];
  const float* fc1_w  = (const float*)d_in[8];
  const float* fc1_b  = (const float*)d_in[9];
  const float* fc2_w  = (const float*)d_in[10];
  const float* fc2_b  = (const float*)d_in[11];
  const float* t_w1   = (const float*)d_in[12];
  const float* t_b1   = (const float*)d_in[13];
  const float* t_w2   = (const float*)d_in[14];
  const float* t_b2   = (const float*)d_in[15];
  const float* h_w1   = (const float*)d_in[16];
  const float* h_b1   = (const float*)d_in[17];
  const float* h_w2   = (const float*)d_in[18];
  const float* h_b2   = (const float*)d_in[19];
  const int*   hop    = (const int*)d_in[20];

  const size_t WS_NEED = 40613504u;
  if (ws_size < WS_NEED) return;

  char* ws = (char*)d_ws;
  ushort* h_bf   = (ushort*)(ws);
  ushort* q_bf   = (ushort*)(ws + 5734400);
  ushort* k_bf   = (ushort*)(ws + 15564800);
  ushort* v_bf   = (ushort*)(ws + 25395200);
  ushort* o_bf   = (ushort*)(ws + 30924800);
  float*  x1     = (float*) (ws);
  ushort* h1_bf  = (ushort*)(ws + 11468800);
  ushort* g_bf   = (ushort*)(ws + 17203200);
  ushort* qkv_wb = (ushort*)(ws + 39321600);
  ushort* proj_wb= (ushort*)(ws + 39636992);
  ushort* fc1_wb = (ushort*)(ws + 39751680);
  ushort* fc2_wb = (ushort*)(ws + 40153088);
  float*  bt     = (float*) (ws + 40595456);
  float*  bh     = bt + 127*6;

  hipMemsetAsync(ws + 5734400, 0, 19660800, stream);   // q/k pad cols
  hipMemsetAsync(ws + 30924800, 0, 5734400, stream);   // o pad cols

  bias_tables_kernel<<<1, 256, 0, stream>>>(t_w1, t_b1, t_w2, t_b2,
                                            h_w1, h_b1, h_w2, h_b2, hop, bt, bh);

  convpad_kernel<<<(704*224+255)/256, 256, 0, stream>>>(qkv_w,  qkv_wb, 648, 216, 224, 704*224);
  convpad_kernel<<<(256*224+255)/256, 256, 0, stream>>>(proj_w, proj_wb,216, 216, 224, 256*224);
  convpad_kernel<<<(896*224+255)/256, 256, 0, stream>>>(fc1_w,  fc1_wb, 864, 216, 224, 896*224);
  convpad_kernel<<<(256*864+255)/256, 256, 0, stream>>>(fc2_w,  fc2_wb, 216, 864, 864, 256*864);

  ln_kernel<<<MROWS/4, 256, 0, stream>>>(x, norm_w, norm_b, h_bf);

  gemm_mfma<EPI_QKV, 32><<<dim3(MROWS/128, 11), 256, 0, stream>>>(
      h_bf, qkv_wb, nullptr, nullptr, nullptr, q_bf, k_bf, v_bf, 648, 224);

  attn_kernel<<<1200, 256, 0, stream>>>(q_bf, k_bf, v_bf, bt, bh, o_bf);

  gemm_mfma<EPI_PROJ, 16><<<dim3(MROWS/64, 4), 256, 0, stream>>>(
      o_bf, proj_wb, proj_b, x, x1, nullptr, nullptr, nullptr, 216, 224);

  ln_kernel<<<MROWS/4, 256, 0, stream>>>(x1, norm1_w, norm1_b, h1_bf);

  gemm_mfma<EPI_FC1, 32><<<dim3(MROWS/128, 14), 256, 0, stream>>>(
      h1_bf, fc1_wb, fc1_b, nullptr, nullptr, g_bf, nullptr, nullptr, 864, 224);

  gemm_mfma<EPI_FC2, 16><<<dim3(MROWS/64, 4), 256, 0, stream>>>(
      g_bf, fc2_wb, fc2_b, x1, (float*)d_out, nullptr, nullptr, nullptr, 216, 864);
}

// Round 7
// 186.975 us; speedup vs baseline: 3.9861x; 1.0733x over previous
//
#include <hip/hip_runtime.h>
#include <hip/hip_bf16.h>

// Round 6: round-5 design with compile fix (exp2f instead of __exp2f).
// Bias-in-MFMA attention (hop bias via Q/K pad dims), no-max softmax,
// pre-permuted/swizzled V with glds16 staging, double-buffered K/V.
// N=8, T=1600 (F=64 x V=25), DIM=216, H=6, HD=36.

#define NHEAD  6
#define TLEN   1600
#define DIMC   216
#define HDIM   36
#define NBATCH 8
#define MROWS  12800
#define QK_SCALE (1.f/6.f)
#define C2EXP 0.24022650695910072f   // 1/(6 ln2)

typedef __attribute__((ext_vector_type(8))) short s16x8;
typedef __attribute__((ext_vector_type(4))) float f32x4;

#define MFMA16(a,b,c) __builtin_amdgcn_mfma_f32_16x16x32_bf16((a),(b),(c),0,0,0)

__device__ __forceinline__ float  bf2f(ushort u){ return __uint_as_float((uint)u << 16); }
__device__ __forceinline__ ushort f2bf(float f){
  uint u = __float_as_uint(f);
  u += 0x7FFFu + ((u >> 16) & 1u);      // RNE
  return (ushort)(u >> 16);
}
__device__ __forceinline__ uint cvtpk_bf16(float lo, float hi){
  uint r;
  asm("v_cvt_pk_bf16_f32 %0, %1, %2" : "=v"(r) : "v"(lo), "v"(hi));
  return r;
}
__device__ __forceinline__ void glds16(const ushort* g, ushort* l){
  __builtin_amdgcn_global_load_lds(
      (const __attribute__((address_space(1))) void*)g,
      (__attribute__((address_space(3))) void*)l, 16, 0, 0);
}

// ---------------------------------------------------------------------------
// Bias tables: bias_t[6][127] scaled by 1/(6 ln2); bias_h[6][625] RAW.
// ---------------------------------------------------------------------------
__global__ __launch_bounds__(256) void bias_tables_kernel(
    const float* __restrict__ t_w1, const float* __restrict__ t_b1,
    const float* __restrict__ t_w2, const float* __restrict__ t_b2,
    const float* __restrict__ h_w1, const float* __restrict__ h_b1,
    const float* __restrict__ h_w2, const float* __restrict__ h_b2,
    const int*  __restrict__ hop,
    float* __restrict__ bias_t, float* __restrict__ bias_h)
{
  __shared__ float tblh[16][NHEAD];
  int tid = threadIdx.x;
  if (tid < 127) {
    float xi = (float)(tid - 63);
    float acc[NHEAD] = {0.f,0.f,0.f,0.f,0.f,0.f};
    for (int d = 0; d < DIMC; ++d) {
      float r = fmaxf(fmaf(xi, t_w1[d], t_b1[d]), 0.f);
      #pragma unroll
      for (int h = 0; h < NHEAD; ++h) acc[h] = fmaf(r, t_w2[h*DIMC + d], acc[h]);
    }
    #pragma unroll
    for (int h = 0; h < NHEAD; ++h)
      bias_t[h*127 + tid] = (acc[h] + t_b2[h]) * C2EXP;
  }
  if (tid >= 128 && tid < 144) {
    int i = tid - 128;
    float xi = (float)i;
    float acc[NHEAD] = {0.f,0.f,0.f,0.f,0.f,0.f};
    for (int d = 0; d < DIMC; ++d) {
      float r = fmaxf(fmaf(xi, h_w1[d], h_b1[d]), 0.f);
      #pragma unroll
      for (int h = 0; h < NHEAD; ++h) acc[h] = fmaf(r, h_w2[h*DIMC + d], acc[h]);
    }
    #pragma unroll
    for (int h = 0; h < NHEAD; ++h) tblh[i][h] = acc[h] + h_b2[h];   // RAW
  }
  __syncthreads();
  for (int i = tid; i < NHEAD*625; i += 256) {
    int h = i / 625, e = i - h*625;
    bias_h[i] = tblh[hop[e]][h];
  }
}

// ---------------------------------------------------------------------------
// Pad-fill: write Q pad cols 36..63 = onehot(vq), K pad cols 36..60 = bh[j][vk]
// (raw), 61..63 = 0, for every (nh, t).  Replaces the q/k pad memset.
// ---------------------------------------------------------------------------
__global__ __launch_bounds__(256) void padfill_kernel(
    const float* __restrict__ bh_raw,   // [6][25][25]
    ushort* __restrict__ qb, ushort* __restrict__ kb)
{
  int idx = blockIdx.x*256 + threadIdx.x;
  if (idx >= NBATCH*NHEAD*TLEN) return;
  int nh = idx / TLEN, t = idx - nh*TLEN;
  int h = nh % NHEAD;
  int vk = t % 25;
  size_t row = ((size_t)nh*TLEN + t) << 6;
  ushort4 z = {0,0,0,0};
  #pragma unroll
  for (int i = 0; i < 7; ++i) *(ushort4*)(qb + row + 36 + i*4) = z;
  qb[row + 36 + vk] = 0x3F80;   // 1.0 bf16 at onehot(vq)
  #pragma unroll
  for (int j = 0; j < 25; ++j)
    kb[row + 36 + j] = f2bf(bh_raw[h*625 + j*25 + vk]);
  kb[row + 61] = 0; kb[row + 62] = 0; kb[row + 63] = 0;
}

// ---------------------------------------------------------------------------
// Weight convert+pad: fp32 [N][K] -> bf16 [Npad][Kpad] (zeros in pad)
// ---------------------------------------------------------------------------
__global__ __launch_bounds__(256) void convpad_kernel(
    const float* __restrict__ src, ushort* __restrict__ dst,
    int N, int K, int Kpad, int total)
{
  int idx = blockIdx.x*256 + threadIdx.x;
  if (idx >= total) return;
  int n = idx / Kpad, k = idx - n*Kpad;
  float v = (n < N && k < K) ? src[n*K + k] : 0.f;
  dst[idx] = f2bf(v);
}

// ---------------------------------------------------------------------------
// LayerNorm: fp32 in (stride 216) -> bf16 out (stride 224, cols 216..223 = 0)
// ---------------------------------------------------------------------------
__global__ __launch_bounds__(256) void ln_kernel(
    const float* __restrict__ x, const float* __restrict__ w,
    const float* __restrict__ b, ushort* __restrict__ out)
{
  int lane = threadIdx.x & 63;
  int row  = blockIdx.x * 4 + (threadIdx.x >> 6);
  const float* xr = x + (size_t)row * DIMC;
  float v0 = xr[lane];
  float v1 = xr[lane + 64];
  float v2 = xr[lane + 128];
  float v3 = (lane < 24) ? xr[lane + 192] : 0.f;
  float s1 = v0 + v1 + v2 + v3;
  float s2 = v0*v0 + v1*v1 + v2*v2 + v3*v3;
  #pragma unroll
  for (int m = 32; m; m >>= 1) { s1 += __shfl_xor(s1, m); s2 += __shfl_xor(s2, m); }
  float mu  = s1 * (1.f/216.f);
  float var = fmaxf(s2 * (1.f/216.f) - mu*mu, 0.f);
  float rs  = rsqrtf(var + 1e-5f);
  ushort* orow = out + (size_t)row * 224;
  orow[lane]       = f2bf((v0-mu)*rs*w[lane]       + b[lane]);
  orow[lane+64]    = f2bf((v1-mu)*rs*w[lane+64]    + b[lane+64]);
  orow[lane+128]   = f2bf((v2-mu)*rs*w[lane+128]   + b[lane+128]);
  if (lane < 32) {
    float vv = (lane < 24) ? (v3-mu)*rs*w[lane+192] + b[lane+192] : 0.f;
    orow[lane+192] = f2bf(vv);
  }
}

// ---------------------------------------------------------------------------
// MFMA GEMM (as round 4; QKV epilogue stores V permuted + XOR-swizzled)
// ---------------------------------------------------------------------------
enum { EPI_QKV = 0, EPI_PROJ = 1, EPI_FC1 = 2, EPI_FC2 = 3 };

template<int EPI, int WM>
__global__ __launch_bounds__(256) void gemm_mfma(
    const ushort* __restrict__ A, const ushort* __restrict__ B,
    const float* __restrict__ bias, const float* __restrict__ res,
    float* __restrict__ outf, ushort* __restrict__ oq,
    ushort* __restrict__ ok, ushort* __restrict__ ov,
    int N, int K)
{
  constexpr int BM = WM*4;
  constexpr int NMF = WM/16;
  constexpr int APASS = (BM*4)/256;
  __shared__ ushort As[2][BM*32];
  __shared__ ushort Bs[2][64*32];

  int tid = threadIdx.x;
  int w = tid >> 6, lane = tid & 63, l15 = lane & 15, g = lane >> 4;
  int row0 = blockIdx.x*BM, col0 = blockIdx.y*64;
  const int NT = K >> 5;

  f32x4 acc[NMF][4];
  #pragma unroll
  for (int i = 0; i < NMF; ++i)
    #pragma unroll
    for (int nf = 0; nf < 4; ++nf) acc[i][nf] = (f32x4){0.f,0.f,0.f,0.f};

  #define STAGE(buf, t)                                                       \
  {                                                                           \
    int k0 = (t) << 5;                                                        \
    _Pragma("unroll")                                                         \
    for (int p = 0; p < APASS; ++p) {                                         \
      int idx = p*256 + tid;                                                  \
      int mf = idx >> 6, kq = (idx >> 4) & 3, r = idx & 15;                   \
      glds16(A + (size_t)(row0 + mf*16 + r)*K + k0 + kq*8,                    \
             &As[buf][(p*256 + w*64)*8]);                                     \
    }                                                                         \
    {                                                                         \
      int kq = (tid >> 4) & 3, r = tid & 15;                                  \
      glds16(B + (size_t)(col0 + w*16 + r)*K + k0 + kq*8,                     \
             &Bs[buf][w*512]);                                                \
    }                                                                         \
  }

  STAGE(0, 0)
  __syncthreads();

  for (int t = 0; t < NT; ++t) {
    int buf = t & 1;
    if (t + 1 < NT) STAGE(buf ^ 1, t + 1)
    #pragma unroll
    for (int i = 0; i < NMF; ++i) {
      s16x8 a = *(const s16x8*)&As[buf][((w*NMF + i)*64 + g*16 + l15)*8];
      #pragma unroll
      for (int nf = 0; nf < 4; ++nf) {
        s16x8 b = *(const s16x8*)&Bs[buf][(nf*64 + g*16 + l15)*8];
        acc[i][nf] = MFMA16(a, b, acc[i][nf]);
      }
    }
    __syncthreads();
  }
  #undef STAGE

  #pragma unroll
  for (int i = 0; i < NMF; ++i) {
    #pragma unroll
    for (int nf = 0; nf < 4; ++nf) {
      int c = col0 + nf*16 + l15;
      if (c >= N) continue;
      #pragma unroll
      for (int r = 0; r < 4; ++r) {
        int rr = row0 + w*WM + i*16 + 4*g + r;
        float v = acc[i][nf][r];
        if constexpr (EPI == EPI_QKV) {
          int s = c / DIMC, rem = c - s*DIMC;
          int hh = rem / HDIM, d = rem - hh*HDIM;
          int n = rr / TLEN, t = rr - n*TLEN;
          int nh = n*NHEAD + hh;
          ushort bv = f2bf(v);
          if (s == 0)      oq[(((size_t)nh*TLEN + t) << 6) + d] = bv;
          else if (s == 1) ok[(((size_t)nh*TLEN + t) << 6) + d] = bv;
          else {
            // V: k-slot permute + XOR swizzle, layout [nh][d][1600]
            int tile = t >> 6, pos = t & 63;
            int ks2 = pos >> 5, kg = (pos >> 2) & 7, r2 = pos & 3;
            int sg = ((kg & 3) << 1) + (kg >> 2);
            int posp = ks2*32 + sg*4 + r2;
            int grs = (posp >> 3) ^ (d & 7);
            ov[((size_t)nh*HDIM + d)*TLEN + tile*64 + grs*8 + (posp & 7)] = bv;
          }
        } else if constexpr (EPI == EPI_PROJ) {
          outf[(size_t)rr*DIMC + c] = v + bias[c] + res[(size_t)rr*DIMC + c];
        } else if constexpr (EPI == EPI_FC1) {
          v += bias[c];
          v = v * 0.5f * (1.f + erff(v * 0.70710678118654752f));
          oq[(size_t)rr*864 + c] = f2bf(v);
        } else {
          outf[(size_t)rr*DIMC + c] = v + bias[c] + res[(size_t)rr*DIMC + c];
        }
      }
    }
  }
}

// ---------------------------------------------------------------------------
// Attention v2: hop bias comes through the QK MFMA (augmented pad dims);
// no-max softmax (exp2f, clamp 80); glds16 K and V (pre-swizzled sources);
// double-buffered LDS, one barrier per tile.
// ---------------------------------------------------------------------------
__global__ __launch_bounds__(256) void attn_kernel(
    const ushort* __restrict__ qb, const ushort* __restrict__ kb,
    const ushort* __restrict__ vb, const float* __restrict__ bt_g,
    ushort* __restrict__ o)
{
  __shared__ ushort Ks[2][64*64];
  __shared__ ushort Vt[2][48*64];
  __shared__ float bts[128];          // bts[i+1] = bt[i]  (guards idx-1)

  int tid = threadIdx.x;
  int bid = blockIdx.x;
  int c   = bid >> 3;
  int c25 = c / 25;
  int nh  = (bid & 7)*6 + c25;        // XCD r owns batch r's 6 heads
  int qt  = c - c25*25;
  int head = nh % NHEAD, n = nh / NHEAD;
  int wave = tid >> 6, lane = tid & 63;
  int g = lane >> 4, l15 = lane & 15, l7 = l15 & 7;

  if (tid < 127) bts[tid + 1] = bt_g[head*127 + tid];
  if (tid == 127) bts[0] = 0.f;
  {  // zero Vt pad rows 36..47, both buffers
    uint* p0 = (uint*)&Vt[0][36*64];
    uint* p1 = (uint*)&Vt[1][36*64];
    for (int i = tid; i < 384; i += 256) { p0[i] = 0; p1[i] = 0; }
  }

  int qglob = qt*64 + wave*16 + l15;
  const ushort* qrow = qb + (((size_t)nh*TLEN + qglob) << 6);
  s16x8 qf0 = *(const s16x8*)(qrow + g*8);
  s16x8 qf1 = *(const s16x8*)(qrow + 32 + g*8);

  int fq = qglob / 25;

  int vkb[4], ftb[4];
  #pragma unroll
  for (int kt = 0; kt < 4; ++kt) {
    int k0 = kt*16 + 4*g;
    int f0 = (k0 >= 50) ? 2 : (k0 >= 25 ? 1 : 0);
    vkb[kt] = k0 - f0*25;
    ftb[kt] = fq - f0 + 64;           // +63 table offset, +1 bts shift
  }

  float lsum = 0.f;
  f32x4 oa[3];
  #pragma unroll
  for (int dt = 0; dt < 3; ++dt) oa[dt] = (f32x4){0.f,0.f,0.f,0.f};

  const ushort* kbase = kb + ((size_t)nh*TLEN << 6);
  const ushort* vbase = vb + (size_t)nh*HDIM*TLEN;

  #define AST(buf, t0)                                                        \
  {                                                                           \
    _Pragma("unroll")                                                         \
    for (int p = 0; p < 2; ++p) {                                             \
      int gid = p*256 + tid;                                                  \
      int row = gid >> 3, grl = gid & 7;                                      \
      glds16(kbase + (((size_t)((t0) + row)) << 6) + ((grl ^ (row & 7)) << 3),\
             &Ks[buf][(p*256 + wave*64)*8]);                                  \
    }                                                                         \
    {                                                                         \
      int d = tid >> 3, grv = tid & 7;                                        \
      glds16(vbase + (size_t)d*TLEN + (t0) + grv*8,                           \
             &Vt[buf][wave*512]);                                             \
    }                                                                         \
    if (tid < 32) {                                                           \
      int d2 = (256 + tid) >> 3, grv2 = tid & 7;                              \
      glds16(vbase + (size_t)d2*TLEN + (t0) + grv2*8,                         \
             &Vt[buf][2048]);                                                 \
    }                                                                         \
  }

  AST(0, 0)
  __syncthreads();

  for (int t = 0; t < 25; ++t) {
    int buf = t & 1;
    if (t < 24) AST(buf ^ 1, (t + 1) * 64)

    // QK^T (swapped, bias-augmented): sa[kt][r] = S[k=kt*16+4g+r][q=l15] + bh
    f32x4 sa[4];
    #pragma unroll
    for (int kt = 0; kt < 4; ++kt) {
      const ushort* krow = &Ks[buf][(kt*16 + l15) << 6];
      s16x8 a0 = *(const s16x8*)(krow + ((g ^ l7) << 3));
      s16x8 a1 = *(const s16x8*)(krow + (((g + 4) ^ l7) << 3));
      f32x4 z = (f32x4){0.f,0.f,0.f,0.f};
      z = MFMA16(a0, qf0, z);
      sa[kt] = MFMA16(a1, qf1, z);
    }

    // no-max softmax: p = exp2(s_aug * C2 + bt')
    #pragma unroll
    for (int kt = 0; kt < 4; ++kt) {
      float bt0 = bts[ftb[kt]];
      float bt1 = bts[ftb[kt] - 1];
      #pragma unroll
      for (int r = 0; r < 4; ++r) {
        float btv = (vkb[kt] + r >= 25) ? bt1 : bt0;
        float arg = fminf(fmaf(sa[kt][r], C2EXP, btv), 80.f);
        float e = exp2f(arg);
        sa[kt][r] = e;
        lsum += e;
      }
    }

    // PV (swapped): O^T += V^T @ P^T, P^T frag = lane's own packed values
    #pragma unroll
    for (int ks = 0; ks < 2; ++ks) {
      union { s16x8 v; uint u[4]; } pf;
      pf.u[0] = cvtpk_bf16(sa[2*ks][0],   sa[2*ks][1]);
      pf.u[1] = cvtpk_bf16(sa[2*ks][2],   sa[2*ks][3]);
      pf.u[2] = cvtpk_bf16(sa[2*ks+1][0], sa[2*ks+1][1]);
      pf.u[3] = cvtpk_bf16(sa[2*ks+1][2], sa[2*ks+1][3]);
      #pragma unroll
      for (int dt = 0; dt < 3; ++dt) {
        s16x8 a = *(const s16x8*)&Vt[buf][((dt*16 + l15) << 6) +
                                          ((((ks << 2) + g) ^ l7) << 3)];
        oa[dt] = MFMA16(a, pf.v, oa[dt]);
      }
    }

    // advance key indices by 64 (= 2*25 + 14)
    #pragma unroll
    for (int kt = 0; kt < 4; ++kt) {
      vkb[kt] += 14; ftb[kt] -= 2;
      if (vkb[kt] >= 25) { vkb[kt] -= 25; ftb[kt] -= 1; }
    }

    __syncthreads();
  }
  #undef AST

  lsum += __shfl_xor(lsum, 16);
  lsum += __shfl_xor(lsum, 32);
  float inv = 1.f / lsum;
  ushort* orow = o + ((size_t)(n*TLEN + qglob))*224 + head*HDIM;
  #pragma unroll
  for (int dt = 0; dt < 3; ++dt) {
    if (dt < 2 || g == 0) {
      ushort4 st;
      st.x = f2bf(oa[dt][0]*inv);
      st.y = f2bf(oa[dt][1]*inv);
      st.z = f2bf(oa[dt][2]*inv);
      st.w = f2bf(oa[dt][3]*inv);
      *(ushort4*)(orow + dt*16 + 4*g) = st;
    }
  }
}

// ---------------------------------------------------------------------------
extern "C" void kernel_launch(void* const* d_in, const int* in_sizes, int n_in,
                              void* d_out, int out_size, void* d_ws, size_t ws_size,
                              hipStream_t stream) {
  const float* x      = (const float*)d_in[0];
  const float* qkv_w  = (const float*)d_in[1];
  const float* proj_w = (const float*)d_in[2];
  const float* proj_b = (const float*)d_in[3];
  const float* norm_w = (const float*)d_in[4];
  const float* norm_b = (const float*)d_in[5];
  const float* norm1_w= (const float*)d_in[6];
  const float* norm1_b= (const float*)d_in[7];
  const float* fc1_w  = (const float*)d_in[8];
  const float* fc1_b  = (const float*)d_in[9];
  const float* fc2_w  = (const float*)d_in[10];
  const float* fc2_b  = (const float*)d_in[11];
  const float* t_w1   = (const float*)d_in[12];
  const float* t_b1   = (const float*)d_in[13];
  const float* t_w2   = (const float*)d_in[14];
  const float* t_b2   = (const float*)d_in[15];
  const float* h_w1   = (const float*)d_in[16];
  const float* h_b1   = (const float*)d_in[17];
  const float* h_w2   = (const float*)d_in[18];
  const float* h_b2   = (const float*)d_in[19];
  const int*   hop    = (const int*)d_in[20];

  const size_t WS_NEED = 40613504u;
  if (ws_size < WS_NEED) return;

  char* ws = (char*)d_ws;
  ushort* h_bf   = (ushort*)(ws);
  ushort* q_bf   = (ushort*)(ws + 5734400);
  ushort* k_bf   = (ushort*)(ws + 15564800);
  ushort* v_bf   = (ushort*)(ws + 25395200);
  ushort* o_bf   = (ushort*)(ws + 30924800);
  float*  x1     = (float*) (ws);
  ushort* h1_bf  = (ushort*)(ws + 11468800);
  ushort* g_bf   = (ushort*)(ws + 17203200);
  ushort* qkv_wb = (ushort*)(ws + 39321600);
  ushort* proj_wb= (ushort*)(ws + 39636992);
  ushort* fc1_wb = (ushort*)(ws + 39751680);
  ushort* fc2_wb = (ushort*)(ws + 40153088);
  float*  bt     = (float*) (ws + 40595456);
  float*  bh     = bt + 127*6;

  (void)hipMemsetAsync(ws + 30924800, 0, 5734400, stream);   // o pad cols only

  bias_tables_kernel<<<1, 256, 0, stream>>>(t_w1, t_b1, t_w2, t_b2,
                                            h_w1, h_b1, h_w2, h_b2, hop, bt, bh);

  padfill_kernel<<<(NBATCH*NHEAD*TLEN + 255)/256, 256, 0, stream>>>(bh, q_bf, k_bf);

  convpad_kernel<<<(704*224+255)/256, 256, 0, stream>>>(qkv_w,  qkv_wb, 648, 216, 224, 704*224);
  convpad_kernel<<<(256*224+255)/256, 256, 0, stream>>>(proj_w, proj_wb,216, 216, 224, 256*224);
  convpad_kernel<<<(896*224+255)/256, 256, 0, stream>>>(fc1_w,  fc1_wb, 864, 216, 224, 896*224);
  convpad_kernel<<<(256*864+255)/256, 256, 0, stream>>>(fc2_w,  fc2_wb, 216, 864, 864, 256*864);

  ln_kernel<<<MROWS/4, 256, 0, stream>>>(x, norm_w, norm_b, h_bf);

  gemm_mfma<EPI_QKV, 32><<<dim3(MROWS/128, 11), 256, 0, stream>>>(
      h_bf, qkv_wb, nullptr, nullptr, nullptr, q_bf, k_bf, v_bf, 648, 224);

  attn_kernel<<<1200, 256, 0, stream>>>(q_bf, k_bf, v_bf, bt, o_bf);

  gemm_mfma<EPI_PROJ, 16><<<dim3(MROWS/64, 4), 256, 0, stream>>>(
      o_bf, proj_wb, proj_b, x, x1, nullptr, nullptr, nullptr, 216, 224);

  ln_kernel<<<MROWS/4, 256, 0, stream>>>(x1, norm1_w, norm1_b, h1_bf);

  gemm_mfma<EPI_FC1, 32><<<dim3(MROWS/128, 14), 256, 0, stream>>>(
      h1_bf, fc1_wb, fc1_b, nullptr, nullptr, g_bf, nullptr, nullptr, 864, 224);

  gemm_mfma<EPI_FC2, 16><<<dim3(MROWS/64, 4), 256, 0, stream>>>(
      g_bf, fc2_wb, fc2_b, x1, (float*)d_out, nullptr, nullptr, nullptr, 216, 864);
}